// Round 7
// baseline (5718.687 us; speedup 1.0000x reference)
//
#include <hip/hip_runtime.h>
#include <cstdint>
#include <cstddef>

// Problem constants (fixed by reference setup_inputs)
constexpr int Bb = 8;
constexpr int Nn = 8192;
constexpr int Ss = 2048;
constexpr int BS = Bb * Ss;  // 16384

typedef float vfloat2 __attribute__((ext_vector_type(2)));

// ---------------------------------------------------------------------------
// FPS: one block per batch, 512 threads (8 waves), 16 points/thread.
// Serial-latency-chain-bound (r6 lesson): 8 waves halve barrier/tail cost vs
// 1024 threads; 16 pts/thread keeps coords+indices in registers (~145 VGPRs,
// under the 256 cap from __launch_bounds__(512,2) — r3's spill trap avoided).
// Decision math exact f64 with original-index tie-breaks (bit-matches np,
// verified r1-r6). Certified f32 screens/skips (triangle-inequality margins)
// only skip provable non-updates. Morton clustering localizes updates so most
// waves skip screen+argmax via the ballot cache.
// ---------------------------------------------------------------------------
__global__ __launch_bounds__(512, 2) void fps_kernel(const float* __restrict__ xyz,
                                                     float* __restrict__ new_xyz) {
  __shared__ float lx[Nn * 3];             // 96 KB: batch point cloud (orig order)
  __shared__ int cellbuf[4096];            // 16 KB: hist/prefix; aliased as sidx log
  __shared__ int sortedIdx[Nn];            // 32 KB: sorted pos -> original index
  __shared__ float rv32[2][8];
  __shared__ double rv64[2][8];
  __shared__ int ri[2][8];
  int* sidx = cellbuf;                     // selected-index log (setup arrays dead)

  const int b = blockIdx.x;
  const int tid = threadIdx.x;
  const float* xb = xyz + (size_t)b * Nn * 3;
  for (int e = tid; e < Nn * 3; e += 512) lx[e] = xb[e];
  for (int e = tid; e < 4096; e += 512) cellbuf[e] = 0;
  __syncthreads();

  // ---- setup: Morton cell ids + histogram ----
  int mycell[16];
#pragma unroll
  for (int j = 0; j < 16; ++j) {
    const int p = tid + j * 512;
    const float x = lx[p * 3 + 0], y = lx[p * 3 + 1], z = lx[p * 3 + 2];
    int bx = (int)((x + 4.0f) * 2.0f); bx = bx < 0 ? 0 : (bx > 15 ? 15 : bx);
    int by = (int)((y + 4.0f) * 2.0f); by = by < 0 ? 0 : (by > 15 ? 15 : by);
    int bz = (int)((z + 4.0f) * 2.0f); bz = bz < 0 ? 0 : (bz > 15 ? 15 : bz);
    int m = 0;
#pragma unroll
    for (int k = 0; k < 4; ++k) {
      m |= ((bx >> k) & 1) << (3 * k);
      m |= ((by >> k) & 1) << (3 * k + 1);
      m |= ((bz >> k) & 1) << (3 * k + 2);
    }
    mycell[j] = m;
    atomicAdd(&cellbuf[m], 1);
  }
  __syncthreads();
  // ---- exclusive prefix over 4096 cells (Hillis-Steele, in-place) ----
  for (int d = 1; d < 4096; d <<= 1) {
    int v[8];
#pragma unroll
    for (int k = 0; k < 8; ++k) {
      const int e = tid + k * 512;
      v[k] = (e >= d) ? cellbuf[e - d] : 0;
    }
    __syncthreads();
#pragma unroll
    for (int k = 0; k < 8; ++k) cellbuf[tid + k * 512] += v[k];
    __syncthreads();
  }
  {
    int v[8];
#pragma unroll
    for (int k = 0; k < 8; ++k) {
      const int e = tid + k * 512;
      v[k] = (e == 0) ? 0 : cellbuf[e - 1];
    }
    __syncthreads();
#pragma unroll
    for (int k = 0; k < 8; ++k) cellbuf[tid + k * 512] = v[k];
    __syncthreads();
  }
  // ---- scatter: sortedIdx[pos] = original index ----
#pragma unroll
  for (int j = 0; j < 16; ++j) {
    const int pos = atomicAdd(&cellbuf[mycell[j]], 1);
    sortedIdx[pos] = tid + j * 512;
  }
  __syncthreads();

  // ---- load my 16 contiguous sorted points (int4 reads); certified bound ----
  vfloat2 px2[8], py2[8], pz2[8], df2[8];
  double dist[16];
  int sIdxR[16];
  {
    const int4* sp = (const int4*)&sortedIdx[tid * 16];
#pragma unroll
    for (int k = 0; k < 4; ++k) {
      const int4 q = sp[k];
      sIdxR[4 * k + 0] = q.x;
      sIdxR[4 * k + 1] = q.y;
      sIdxR[4 * k + 2] = q.z;
      sIdxR[4 * k + 3] = q.w;
    }
  }
  float cenx = 0.f, ceny = 0.f, cenz = 0.f;
#pragma unroll
  for (int j = 0; j < 16; ++j) {
    const int o = sIdxR[j];
    const float x = lx[o * 3 + 0], y = lx[o * 3 + 1], z = lx[o * 3 + 2];
    if (j & 1) { px2[j >> 1].y = x; py2[j >> 1].y = y; pz2[j >> 1].y = z; }
    else       { px2[j >> 1].x = x; py2[j >> 1].x = y; pz2[j >> 1].x = z; }
    cenx += x; ceny += y; cenz += z;
    dist[j] = 1e10;
    if (j & 1) df2[j >> 1].y = 3.0e38f; else df2[j >> 1].x = 3.0e38f;
  }
  cenx *= 0.0625f; ceny *= 0.0625f; cenz *= 0.0625f;
  float r2max = 0.f;
#pragma unroll
  for (int j = 0; j < 16; ++j) {
    const float dx = px2[j >> 1][j & 1] - cenx;
    const float dy = py2[j >> 1][j & 1] - ceny;
    const float dz = pz2[j >> 1][j & 1] - cenz;
    r2max = fmaxf(r2max, fmaf(dx, dx, fmaf(dy, dy, dz * dz)));
  }
  const float rlane = sqrtf(r2max * (1.0f + 1e-5f)) * (1.0f + 1e-6f);  // certified upper
  float reach = 3.0e38f;                   // sentinel: no skipping until lmax real

  const int lane = tid & 63, wid = tid >> 6;   // wid in 0..7
  int cur = 0;
  double lv = -1.0;                        // per-lane cached local argmax (exact)
  int li = 0x7fffffff;
  float wv32_c = -1.0f;                    // cached wave argmax (all lanes)
  double wv64_c = -1.0;
  int wi_c = 0;
  for (int i = 0; i < Ss; ++i) {
    if (tid == 0) sidx[i] = cur;           // LDS log (visible after barrier)
    const float cxf = lx[cur * 3 + 0], cyf = lx[cur * 3 + 1], czf = lx[cur * 3 + 2];
    // ---- certified lane skip test ----
    const float ex = cxf - cenx, ey = cyf - ceny, ez = czf - cenz;
    const float dc2 = fmaf(ex, ex, fmaf(ey, ey, ez * ez));
    bool changed = false;
    if (!(dc2 * (1.0f - 1e-5f) > reach)) {
      const vfloat2 cx2 = {cxf, cxf}, cy2 = {cyf, cyf}, cz2 = {czf, czf};
      unsigned need = 0;
#pragma unroll
      for (int jj = 0; jj < 8; ++jj) {
        const vfloat2 dx = px2[jj] - cx2;
        const vfloat2 dy = py2[jj] - cy2;
        const vfloat2 dz = pz2[jj] - cz2;
        const vfloat2 d2 = dx * dx + dy * dy + dz * dz;
        need |= (d2.x <= df2[jj].x) ? (1u << (2 * jj)) : 0u;
        need |= (d2.y <= df2[jj].y) ? (1u << (2 * jj + 1)) : 0u;
      }
      if (need) {                          // exact f64 updates
#pragma unroll
        for (int j = 0; j < 16; ++j) {
          if (need & (1u << j)) {
            const float pxs = px2[j >> 1][j & 1];
            const float pys = py2[j >> 1][j & 1];
            const float pzs = pz2[j >> 1][j & 1];
            double dx = __dsub_rn((double)pxs, (double)cxf);
            double dy = __dsub_rn((double)pys, (double)cyf);
            double dz = __dsub_rn((double)pzs, (double)czf);
            double d = __dadd_rn(__dadd_rn(__dmul_rn(dx, dx), __dmul_rn(dy, dy)),
                                 __dmul_rn(dz, dz));
            if (d < dist[j]) {
              dist[j] = d;
              const float dfn = (float)d * 1.000002f;  // certified upper bound
              if (j & 1) df2[j >> 1].y = dfn; else df2[j >> 1].x = dfn;
              changed = true;
            }
          }
        }
      }
    }
    const unsigned long long anyb = __ballot(changed);
    if (changed) {
      // rescan local max (exact, original-index tie-break; indices in regs)
      lv = -1.0;
      li = 0x7fffffff;
#pragma unroll
      for (int j = 0; j < 16; ++j) {
        const double d = dist[j];
        if (d > lv) { lv = d; li = sIdxR[j]; }
        else if (d == lv) { li = sIdxR[j] < li ? sIdxR[j] : li; }
      }
      // refresh lmax + reach (changed lanes only)
      float lmax = fmaxf(df2[0].x, df2[0].y);
#pragma unroll
      for (int jj = 1; jj < 8; ++jj) { lmax = fmaxf(lmax, df2[jj].x); lmax = fmaxf(lmax, df2[jj].y); }
      const float s = rlane + sqrtf(lmax) * (1.0f + 1e-6f);
      reach = s * s * (1.0f + 1e-5f);
    }
    if (anyb) {                            // wave argmax only if wave changed
      const float lv32 = (float)lv;
      float m32 = lv32;
#pragma unroll
      for (int off = 1; off < 64; off <<= 1) m32 = fmaxf(m32, __shfl_xor(m32, off));
      const unsigned long long em = __ballot(lv32 == m32);
      if (__popcll(em) == 1) {             // unique f32 max == f64 argmax
        const int w = (int)__builtin_ctzll(em);
        wi_c = __shfl(li, w);
        wv64_c = __shfl(lv, w);
        wv32_c = m32;
      } else {                             // rare: f64 argmax w/ idx tie-break
        double bv = lv;
        int bi = li;
#pragma unroll
        for (int off = 1; off < 64; off <<= 1) {
          double ov = __shfl_xor(bv, off);
          int oi = __shfl_xor(bi, off);
          if (ov > bv || (ov == bv && oi < bi)) { bv = ov; bi = oi; }
        }
        wv64_c = bv;
        wi_c = bi;
        wv32_c = (float)bv;
      }
    }
    const int pb = i & 1;
    if (lane == 0) { rv32[pb][wid] = wv32_c; rv64[pb][wid] = wv64_c; ri[pb][wid] = wi_c; }
    __syncthreads();
    // ---- block reduce: f32 value max over 8 entries, unique-winner path ----
    const float mine = rv32[pb][lane & 7];
    float g32 = mine;
#pragma unroll
    for (int off = 1; off < 8; off <<= 1) g32 = fmaxf(g32, __shfl_xor(g32, off));
    const unsigned long long bm = __ballot((lane < 8) && (mine == g32));
    if (__popcll(bm) == 1) {
      cur = ri[pb][(int)__builtin_ctzll(bm)];
    } else {                               // rare: f64 among f32-tied entries
      double gv = -1.0;
      int gi = 0x7fffffff;
      unsigned mm = (unsigned)bm;
      while (mm) {
        const int w = (int)__builtin_ctz(mm);
        mm &= mm - 1;
        const double ov = rv64[pb][w];
        const int oi = ri[pb][w];
        if (ov > gv || (ov == gv && oi < gi)) { gv = ov; gi = oi; }
      }
      cur = gi;
    }
  }
  __syncthreads();
  // final gather: new_xyz[i][c] = lx[sidx[i]*3 + c]
  float* nxb = new_xyz + (size_t)b * Ss * 3;
  for (int e = tid; e < Ss * 3; e += 512) {
    const int i = e / 3, c = e - i * 3;
    nxb[e] = lx[sidx[i] * 3 + c];
  }
}

// ---------------------------------------------------------------------------
// Ball query, both scales fused. One wave per center. f64 distance compare
// (bit-matches np). First nsample in-range points in original order; pad with
// first hit (0 if none).
// ---------------------------------------------------------------------------
__global__ __launch_bounds__(256) void ballq_kernel(const float* __restrict__ xyz,
                                                    const float* __restrict__ nxyz,
                                                    int* __restrict__ idx0,
                                                    int* __restrict__ idx1) {
  const int wid = threadIdx.x >> 6, lane = threadIdx.x & 63;
  const int bs = blockIdx.x * 4 + wid;
  const int b = bs >> 11;  // S = 2048
  const float* xb = xyz + (size_t)b * Nn * 3;
  const double cx = (double)nxyz[bs * 3 + 0];
  const double cy = (double)nxyz[bs * 3 + 1];
  const double cz = (double)nxyz[bs * 3 + 2];
  const double R0 = 0.4 * 0.4, R1 = 0.8 * 0.8;
  int cnt0 = 0, cnt1 = 0, first0 = 0, first1 = 0;
  const unsigned long long lmask = (1ull << lane) - 1ull;
  for (int base = 0; base < Nn; base += 64) {
    const int p = base + lane;
    double dx = __dsub_rn((double)xb[p * 3 + 0], cx);
    double dy = __dsub_rn((double)xb[p * 3 + 1], cy);
    double dz = __dsub_rn((double)xb[p * 3 + 2], cz);
    double d2 = __dadd_rn(__dadd_rn(__dmul_rn(dx, dx), __dmul_rn(dy, dy)), __dmul_rn(dz, dz));
    const bool in0 = d2 < R0, in1 = d2 < R1;
    unsigned long long m0 = __ballot(in0);
    unsigned long long m1 = __ballot(in1);
    if (cnt0 < 16 && m0) {
      if (cnt0 == 0) first0 = base + __builtin_ctzll(m0);
      int r = (int)__popcll(m0 & lmask);
      if (in0 && cnt0 + r < 16) idx0[bs * 16 + cnt0 + r] = p;
      cnt0 += (int)__popcll(m0);
    }
    if (cnt1 < 32 && m1) {
      if (cnt1 == 0) first1 = base + __builtin_ctzll(m1);
      int r = (int)__popcll(m1 & lmask);
      if (in1 && cnt1 + r < 32) idx1[bs * 32 + cnt1 + r] = p;
      cnt1 += (int)__popcll(m1);
    }
    if (cnt0 >= 16 && cnt1 >= 32) break;
  }
  const int f0 = cnt0 < 16 ? cnt0 : 16;
  for (int j = f0 + lane; j < 16; j += 64) idx0[bs * 16 + j] = first0;
  const int f1 = cnt1 < 32 ? cnt1 : 32;
  for (int j = f1 + lane; j < 32; j += 64) idx1[bs * 32 + j] = first1;
}

// ---------------------------------------------------------------------------
// Generic tall-skinny GEMM with fused input transforms and BN-stat partials.
// Tile: 64 rows x COUT cols, 256 threads, per-thread 4 rows x (COUT/16) cols.
// MODE 0: gather (rel-xyz ++ features) via ball-query idx          (K=67)
// MODE 1: x = relu(bn(prev_raw)) from 64-ch buffer (in-place safe) (K=64)
// MODE 2: x = concat(relu(bn(pool0)), relu(bn(pool1)))             (K=256)
// MODE 3: x = plain read (already-normalized h)                    (K=256)
// POOL  : write per-group (NS) max of raw output instead of full rows.
// Every block writes per-channel (sum, sumsq) partials to P[ch][block].
// ---------------------------------------------------------------------------
template <int COUT, int KTOT, int MODE, int NS, bool POOL, bool BIAS>
__global__ __launch_bounds__(256) void mlp_gemm(
    const float* __restrict__ xin, const float* __restrict__ xin2,
    const float* __restrict__ bnp, const float* __restrict__ bnp2,
    const float* __restrict__ w, const float* __restrict__ bias,
    const int* __restrict__ gidx, const float* __restrict__ xyz,
    const float* __restrict__ nxyz, const float* __restrict__ feats,
    float* __restrict__ out, float* __restrict__ P) {
  constexpr int KC = (KTOT <= 68) ? KTOT : 32;     // K chunk
  constexpr int NCH = (KTOT + KC - 1) / KC;
  constexpr int TC = COUT / 16;                    // cols per thread
  constexpr int XPAD = KC + 1;
  constexpr int XSZ = 64 * XPAD;
  constexpr int EPI = (POOL ? 48 : 32) * COUT;
  constexpr int SM = (XSZ + KC * COUT > EPI) ? (XSZ + KC * COUT) : EPI;
  __shared__ float smem[SM];
  float* xS = smem;
  float* wS = smem + XSZ;

  const int tid = threadIdx.x;
  const int cg = tid & 15, rg = tid >> 4;
  const int row0 = blockIdx.x * 64;
  float acc[4][TC];
#pragma unroll
  for (int i = 0; i < 4; ++i)
#pragma unroll
    for (int t = 0; t < TC; ++t) acc[i][t] = 0.f;

  for (int ch = 0; ch < NCH; ++ch) {
    const int k0 = ch * KC;
    if (ch) __syncthreads();
    // ---- stage x tile [64 rows][KC] (row-major, padded) ----
    for (int e = tid; e < 64 * KC; e += 256) {
      const int r = e / KC, kk = e - r * KC;
      const int kg = k0 + kk;
      const int rowg = row0 + r;
      float v;
      if constexpr (MODE == 0) {
        const int bs = rowg / NS;
        const int p = gidx[rowg];
        const int bb = bs >> 11;
        if (kg < 3)
          v = xyz[(bb * Nn + p) * 3 + kg] - nxyz[bs * 3 + kg];
        else
          v = feats[((bb * Nn + p) << 6) + (kg - 3)];
      } else if constexpr (MODE == 1) {
        v = fmaxf((xin[(size_t)rowg * 64 + kg] - bnp[kg]) * bnp[64 + kg], 0.f);
      } else if constexpr (MODE == 2) {
        if (kg < 128)
          v = fmaxf((xin[(size_t)rowg * 128 + kg] - bnp[kg]) * bnp[128 + kg], 0.f);
        else {
          const int k2 = kg - 128;
          v = fmaxf((xin2[(size_t)rowg * 128 + k2] - bnp2[k2]) * bnp2[128 + k2], 0.f);
        }
      } else {
        v = xin[(size_t)rowg * 256 + kg];
      }
      xS[r * XPAD + kk] = v;
    }
    // ---- stage w chunk [KC][COUT] ----
    for (int e = tid; e < KC * COUT; e += 256) {
      const int kk = e / COUT, c = e - kk * COUT;
      wS[kk * COUT + c] = w[(size_t)(k0 + kk) * COUT + c];
    }
    __syncthreads();
    // ---- FMA loop ----
    for (int kk = 0; kk < KC; ++kk) {
      float xr[4];
#pragma unroll
      for (int i = 0; i < 4; ++i) xr[i] = xS[(rg * 4 + i) * XPAD + kk];
#pragma unroll
      for (int t = 0; t < TC; t += 4) {
        const float4 wv = *(const float4*)&wS[kk * COUT + cg * TC + t];
#pragma unroll
        for (int i = 0; i < 4; ++i) {
          acc[i][t + 0] = fmaf(xr[i], wv.x, acc[i][t + 0]);
          acc[i][t + 1] = fmaf(xr[i], wv.y, acc[i][t + 1]);
          acc[i][t + 2] = fmaf(xr[i], wv.z, acc[i][t + 2]);
          acc[i][t + 3] = fmaf(xr[i], wv.w, acc[i][t + 3]);
        }
      }
    }
  }
  __syncthreads();  // smem reuse below
  if constexpr (BIAS) {
#pragma unroll
    for (int t = 0; t < TC; ++t) {
      const float bv = bias[cg * TC + t];
#pragma unroll
      for (int i = 0; i < 4; ++i) acc[i][t] += bv;
    }
  }
  // ---- per-block BN partials (+ group max for POOL) ----
  float* ssum = smem;
  float* ssq = smem + 16 * COUT;
  float* pbuf = smem + 32 * COUT;
  const int colb = cg * TC;
#pragma unroll
  for (int t = 0; t < TC; ++t) {
    float s = 0.f, q = 0.f, m = -3.4e38f;
#pragma unroll
    for (int i = 0; i < 4; ++i) {
      const float v = acc[i][t];
      s += v;
      q = fmaf(v, v, q);
      m = fmaxf(m, v);
    }
    ssum[rg * COUT + colb + t] = s;
    ssq[rg * COUT + colb + t] = q;
    if constexpr (POOL) pbuf[rg * COUT + colb + t] = m;
  }
  __syncthreads();
  const int gX = gridDim.x;
  for (int c = tid; c < COUT; c += 256) {
    float s = 0.f, q = 0.f;
#pragma unroll
    for (int rr = 0; rr < 16; ++rr) {
      s += ssum[rr * COUT + c];
      q += ssq[rr * COUT + c];
    }
    P[(size_t)c * gX + blockIdx.x] = s;
    P[(size_t)(COUT + c) * gX + blockIdx.x] = q;
  }
  if constexpr (POOL) {
    constexpr int G = 64 / NS, RPG = NS / 4;
    for (int o = tid; o < G * COUT; o += 256) {
      const int g = o / COUT, c = o - g * COUT;
      float m = pbuf[(g * RPG) * COUT + c];
#pragma unroll
      for (int qq = 1; qq < RPG; ++qq) m = fmaxf(m, pbuf[(g * RPG + qq) * COUT + c]);
      out[(size_t)(blockIdx.x * G + g) * COUT + c] = m;
    }
  } else {
#pragma unroll
    for (int i = 0; i < 4; ++i) {
      float* op = out + (size_t)(row0 + rg * 4 + i) * COUT + colb;
#pragma unroll
      for (int t = 0; t < TC; t += 4) {
        *(float4*)(op + t) = make_float4(acc[i][t], acc[i][t + 1], acc[i][t + 2], acc[i][t + 3]);
      }
    }
  }
}

// ---------------------------------------------------------------------------
// BN finalize: one block per channel, coalesced partial reads, deterministic
// f64 LDS tree reduction -> mu, rstd. bnp layout: [mu(C), rstd(C)].
// ---------------------------------------------------------------------------
__global__ __launch_bounds__(256) void bn_finalize(const float* __restrict__ P, int gX,
                                                   int M, int C, float* __restrict__ bnp) {
  __shared__ double sh[512];
  const int c = blockIdx.x;
  const int tid = threadIdx.x;
  const float* psum = P + (size_t)c * gX;
  const float* psq = P + (size_t)(C + c) * gX;
  double s = 0, q = 0;
  for (int i = tid; i < gX; i += 256) {
    s += (double)psum[i];
    q += (double)psq[i];
  }
  sh[tid] = s;
  sh[256 + tid] = q;
  __syncthreads();
  for (int off = 128; off; off >>= 1) {
    if (tid < off) {
      sh[tid] += sh[tid + off];
      sh[256 + tid] += sh[256 + tid + off];
    }
    __syncthreads();
  }
  if (tid == 0) {
    const double invM = 1.0 / (double)M;
    const double mu = sh[0] * invM;
    const double var = sh[256] * invM - mu * mu;
    bnp[c] = (float)mu;
    bnp[C + c] = (float)(1.0 / sqrt(var + 1e-5));
  }
}

// h = relu(bn(agg_raw)) -> d_out (also consumed by conf layer)
__global__ __launch_bounds__(256) void h_store_kernel(const float* __restrict__ agg,
                                                      const float* __restrict__ bnp,
                                                      float* __restrict__ hout) {
  const int t = blockIdx.x * 256 + threadIdx.x;
  const int c = t & 255;
  const float v = (agg[t] - bnp[c]) * bnp[256 + c];
  hout[t] = fmaxf(v, 0.f);
}

// cls = relu(bn(conf_raw)) @ cls_w + cls_b   (one wave per row)
__global__ __launch_bounds__(256) void cls_kernel(const float* __restrict__ craw,
                                                  const float* __restrict__ bnp,
                                                  const float* __restrict__ clsw,
                                                  const float* __restrict__ clsb,
                                                  float* __restrict__ outc) {
  const int wid = threadIdx.x >> 6, lane = threadIdx.x & 63;
  const int row = blockIdx.x * 4 + wid;
  const float* cr = craw + (size_t)row * 256;
  float a0 = 0.f, a1 = 0.f, a2 = 0.f;
#pragma unroll 4
  for (int k = lane; k < 256; k += 64) {
    float x = fmaxf((cr[k] - bnp[k]) * bnp[256 + k], 0.f);
    a0 = fmaf(x, clsw[k * 3 + 0], a0);
    a1 = fmaf(x, clsw[k * 3 + 1], a1);
    a2 = fmaf(x, clsw[k * 3 + 2], a2);
  }
#pragma unroll
  for (int off = 32; off; off >>= 1) {
    a0 += __shfl_down(a0, off);
    a1 += __shfl_down(a1, off);
    a2 += __shfl_down(a2, off);
  }
  if (lane == 0) {
    outc[row * 3 + 0] = a0 + clsb[0];
    outc[row * 3 + 1] = a1 + clsb[1];
    outc[row * 3 + 2] = a2 + clsb[2];
  }
}

// ---------------------------------------------------------------------------
extern "C" void kernel_launch(void* const* d_in, const int* in_sizes, int n_in,
                              void* d_out, int out_size, void* d_ws, size_t ws_size,
                              hipStream_t stream) {
  (void)in_sizes; (void)n_in; (void)out_size; (void)ws_size;
  const float* xyz = (const float*)d_in[0];
  const float* feats = (const float*)d_in[1];
  const float* w00 = (const float*)d_in[2];
  const float* w01 = (const float*)d_in[3];
  const float* w02 = (const float*)d_in[4];
  const float* w10 = (const float*)d_in[5];
  const float* w11 = (const float*)d_in[6];
  const float* w12 = (const float*)d_in[7];
  const float* aggw = (const float*)d_in[8];
  const float* aggb = (const float*)d_in[9];
  const float* confw = (const float*)d_in[10];
  const float* clsw = (const float*)d_in[11];
  const float* clsb = (const float*)d_in[12];

  float* outp = (float*)d_out;
  float* nxyz = outp;                               // [BS,3]
  float* hout = outp + (size_t)BS * 3;              // [BS,256]
  float* clsout = hout + (size_t)BS * 256;          // [BS,3]

  char* ws = (char*)d_ws;
  const size_t MB = 1u << 20;
  int* idx0 = (int*)(ws + 0);                       // 1 MB
  int* idx1 = (int*)(ws + 1 * MB);                  // 2 MB
  float* bnb = (float*)(ws + 3 * MB);               // bn params (2048 floats)
  float* P = (float*)(ws + 4 * MB);                 // partials, up to 8 MB
  float* pool0 = (float*)(ws + 12 * MB);            // [BS,128]
  float* pool1 = (float*)(ws + 20 * MB);            // [BS,128]
  float* aggraw = (float*)(ws + 28 * MB);           // [BS,256]
  float* confraw = (float*)(ws + 44 * MB);          // [BS,256]
  float* hA = (float*)(ws + 60 * MB);               // [524288,64] (layers 1/2 in-place)

  fps_kernel<<<Bb, 512, 0, stream>>>(xyz, nxyz);
  ballq_kernel<<<BS / 4, 256, 0, stream>>>(xyz, nxyz, idx0, idx1);

  // ---- scale 0 (r=0.4, ns=16), M = 262144 ----
  mlp_gemm<64, 67, 0, 16, false, false><<<4096, 256, 0, stream>>>(
      nullptr, nullptr, nullptr, nullptr, w00, nullptr, idx0, xyz, nxyz, feats, hA, P);
  bn_finalize<<<64, 256, 0, stream>>>(P, 4096, 262144, 64, bnb + 0);
  mlp_gemm<64, 64, 1, 1, false, false><<<4096, 256, 0, stream>>>(
      hA, nullptr, bnb + 0, nullptr, w01, nullptr, nullptr, nullptr, nullptr, nullptr, hA, P);
  bn_finalize<<<64, 256, 0, stream>>>(P, 4096, 262144, 64, bnb + 128);
  mlp_gemm<128, 64, 1, 16, true, false><<<4096, 256, 0, stream>>>(
      hA, nullptr, bnb + 128, nullptr, w02, nullptr, nullptr, nullptr, nullptr, nullptr, pool0, P);
  bn_finalize<<<128, 256, 0, stream>>>(P, 4096, 262144, 128, bnb + 256);

  // ---- scale 1 (r=0.8, ns=32), M = 524288 ----
  mlp_gemm<64, 67, 0, 32, false, false><<<8192, 256, 0, stream>>>(
      nullptr, nullptr, nullptr, nullptr, w10, nullptr, idx1, xyz, nxyz, feats, hA, P);
  bn_finalize<<<64, 256, 0, stream>>>(P, 8192, 524288, 64, bnb + 512);
  mlp_gemm<64, 64, 1, 1, false, false><<<8192, 256, 0, stream>>>(
      hA, nullptr, bnb + 512, nullptr, w11, nullptr, nullptr, nullptr, nullptr, nullptr, hA, P);
  bn_finalize<<<64, 256, 0, stream>>>(P, 8192, 524288, 64, bnb + 640);
  mlp_gemm<128, 64, 1, 32, true, false><<<8192, 256, 0, stream>>>(
      hA, nullptr, bnb + 640, nullptr, w12, nullptr, nullptr, nullptr, nullptr, nullptr, pool1, P);
  bn_finalize<<<128, 256, 0, stream>>>(P, 8192, 524288, 128, bnb + 768);

  // ---- aggregation: concat(bn3_0(pool0), bn3_1(pool1)) @ agg_w + agg_b ----
  mlp_gemm<256, 256, 2, 1, false, true><<<256, 256, 0, stream>>>(
      pool0, pool1, bnb + 256, bnb + 768, aggw, aggb, nullptr, nullptr, nullptr, nullptr, aggraw, P);
  bn_finalize<<<256, 256, 0, stream>>>(P, 256, 16384, 256, bnb + 1024);
  h_store_kernel<<<BS, 256, 0, stream>>>(aggraw, bnb + 1024, hout);

  // ---- confidence hidden layer ----
  mlp_gemm<256, 256, 3, 1, false, false><<<256, 256, 0, stream>>>(
      hout, nullptr, nullptr, nullptr, confw, nullptr, nullptr, nullptr, nullptr, nullptr, confraw, P);
  bn_finalize<<<256, 256, 0, stream>>>(P, 256, 16384, 256, bnb + 1536);

  // ---- classifier ----
  cls_kernel<<<BS / 4, 256, 0, stream>>>(confraw, bnb + 1536, clsw, clsb, clsout);
}

// Round 8
// 4517.781 us; speedup vs baseline: 1.2658x; 1.2658x over previous
//
#include <hip/hip_runtime.h>
#include <cstdint>
#include <cstddef>

// Problem constants (fixed by reference setup_inputs)
constexpr int Bb = 8;
constexpr int Nn = 8192;
constexpr int Ss = 2048;
constexpr int BS = Bb * Ss;  // 16384

typedef float vfloat2 __attribute__((ext_vector_type(2)));

// ---------------------------------------------------------------------------
// FPS: one block per batch, 512 threads (8 waves), 16 points/thread, strided
// ownership (p = tid + j*512 — indices are ALU, zero index registers).
// NO clustering: at 2 waves/SIMD there is no issue contention for the skip
// logic to relieve, and r6/r7 showed it only lengthens the serial chain.
// __launch_bounds__(512,1): 512-VGPR budget -> ~155 live regs, no spill
// (r3/r7 regressions were both spill-driven; r7's (512,2) capped at 128+scratch).
// Decision math exact f64 (bit-matches np, verified r1-r7): certified f32
// screening (distf = (float)dist * 1.000002 upper bound), value-only f32
// wave/block maxima with uniqueness ballots, exact f64 fallbacks on collision,
// original-index tie-breaks (j asc => smaller index kept by strict >).
// LDS index log; single global gather at the end (no vmcnt drain at barrier).
// ---------------------------------------------------------------------------
__global__ __launch_bounds__(512, 1) void fps_kernel(const float* __restrict__ xyz,
                                                     float* __restrict__ new_xyz) {
  __shared__ float lx[Nn * 3];             // 96 KB: batch point cloud
  __shared__ int sidx[Ss];                 // 8 KB: selected-index log
  __shared__ float rv32[2][8];
  __shared__ double rv64[2][8];
  __shared__ int ri[2][8];
  const int b = blockIdx.x;
  const int tid = threadIdx.x;
  const float* xb = xyz + (size_t)b * Nn * 3;
  for (int e = tid; e < Nn * 3; e += 512) lx[e] = xb[e];
  __syncthreads();

  vfloat2 px2[8], py2[8], pz2[8], df2[8];
  double dist[16];
#pragma unroll
  for (int jj = 0; jj < 8; ++jj) {
    const int p0 = tid + (2 * jj) * 512, p1 = tid + (2 * jj + 1) * 512;
    px2[jj] = (vfloat2){lx[p0 * 3 + 0], lx[p1 * 3 + 0]};
    py2[jj] = (vfloat2){lx[p0 * 3 + 1], lx[p1 * 3 + 1]};
    pz2[jj] = (vfloat2){lx[p0 * 3 + 2], lx[p1 * 3 + 2]};
    df2[jj] = (vfloat2){3.0e38f, 3.0e38f};   // force exact path on first touch
    dist[2 * jj] = 1e10;
    dist[2 * jj + 1] = 1e10;
  }
  const int lane = tid & 63, wid = tid >> 6;   // wid in 0..7
  int cur = 0;
  double lv = -1.0;                        // per-lane cached local argmax (exact)
  int li = tid;
  float wv32_c = -1.0f;                    // cached wave argmax (all lanes)
  double wv64_c = -1.0;
  int wi_c = 0;
  for (int i = 0; i < Ss; ++i) {
    if (tid == 0) sidx[i] = cur;           // LDS log (visible after barrier)
    const float cxf = lx[cur * 3 + 0], cyf = lx[cur * 3 + 1], czf = lx[cur * 3 + 2];
    const vfloat2 cx2 = {cxf, cxf}, cy2 = {cyf, cyf}, cz2 = {czf, czf};
    // ---- packed-f32 screening: which j might update? ----
    unsigned need = 0;
#pragma unroll
    for (int jj = 0; jj < 8; ++jj) {
      const vfloat2 dx = px2[jj] - cx2;
      const vfloat2 dy = py2[jj] - cy2;
      const vfloat2 dz = pz2[jj] - cz2;
      const vfloat2 d2 = dx * dx + dy * dy + dz * dz;
      need |= (d2.x <= df2[jj].x) ? (1u << (2 * jj)) : 0u;
      need |= (d2.y <= df2[jj].y) ? (1u << (2 * jj + 1)) : 0u;
    }
    bool changed = false;
    if (need) {                            // rare path: exact f64 updates
#pragma unroll
      for (int j = 0; j < 16; ++j) {
        if (need & (1u << j)) {
          const float pxs = px2[j >> 1][j & 1];
          const float pys = py2[j >> 1][j & 1];
          const float pzs = pz2[j >> 1][j & 1];
          double dx = __dsub_rn((double)pxs, (double)cxf);
          double dy = __dsub_rn((double)pys, (double)cyf);
          double dz = __dsub_rn((double)pzs, (double)czf);
          double d = __dadd_rn(__dadd_rn(__dmul_rn(dx, dx), __dmul_rn(dy, dy)),
                               __dmul_rn(dz, dz));
          if (d < dist[j]) {
            dist[j] = d;
            const float dfn = (float)d * 1.000002f;  // certified upper bound
            if (j & 1) df2[j >> 1].y = dfn; else df2[j >> 1].x = dfn;
            changed = true;
          }
        }
      }
    }
    const unsigned long long anyb = __ballot(changed);
    if (changed) {                         // rescan local max only when needed
      lv = -1.0;
      li = 0;
#pragma unroll
      for (int j = 0; j < 16; ++j) {
        if (dist[j] > lv) { lv = dist[j]; li = tid + j * 512; }  // j asc => smallest idx on tie
      }
    }
    if (anyb) {                            // wave argmax only if wave changed
      const float lv32 = (float)lv;
      float m32 = lv32;
#pragma unroll
      for (int off = 1; off < 64; off <<= 1) m32 = fmaxf(m32, __shfl_xor(m32, off));
      const unsigned long long em = __ballot(lv32 == m32);
      if (__popcll(em) == 1) {             // unique f32 max == f64 argmax
        const int w = (int)__builtin_ctzll(em);
        wi_c = __shfl(li, w);
        wv64_c = __shfl(lv, w);
        wv32_c = m32;
      } else {                             // rare: f64 argmax w/ idx tie-break
        double bv = lv;
        int bi = li;
#pragma unroll
        for (int off = 1; off < 64; off <<= 1) {
          double ov = __shfl_xor(bv, off);
          int oi = __shfl_xor(bi, off);
          if (ov > bv || (ov == bv && oi < bi)) { bv = ov; bi = oi; }
        }
        wv64_c = bv;
        wi_c = bi;
        wv32_c = (float)bv;
      }
    }
    const int pb = i & 1;
    if (lane == 0) { rv32[pb][wid] = wv32_c; rv64[pb][wid] = wv64_c; ri[pb][wid] = wi_c; }
    __syncthreads();
    // ---- block reduce: f32 value max over 8 entries, unique-winner path ----
    const float mine = rv32[pb][lane & 7];
    float g32 = mine;
#pragma unroll
    for (int off = 1; off < 8; off <<= 1) g32 = fmaxf(g32, __shfl_xor(g32, off));
    const unsigned long long bm = __ballot((lane < 8) && (mine == g32));
    if (__popcll(bm) == 1) {
      cur = ri[pb][(int)__builtin_ctzll(bm)];
    } else {                               // rare: f64 among f32-tied entries
      double gv = -1.0;
      int gi = 0x7fffffff;
      unsigned mm = (unsigned)bm;
      while (mm) {
        const int w = (int)__builtin_ctz(mm);
        mm &= mm - 1;
        const double ov = rv64[pb][w];
        const int oi = ri[pb][w];
        if (ov > gv || (ov == gv && oi < gi)) { gv = ov; gi = oi; }
      }
      cur = gi;
    }
  }
  __syncthreads();
  // final gather: new_xyz[i][c] = lx[sidx[i]*3 + c]
  float* nxb = new_xyz + (size_t)b * Ss * 3;
  for (int e = tid; e < Ss * 3; e += 512) {
    const int i = e / 3, c = e - i * 3;
    nxb[e] = lx[sidx[i] * 3 + c];
  }
}

// ---------------------------------------------------------------------------
// Ball query, both scales fused. One wave per center. f64 distance compare
// (bit-matches np). First nsample in-range points in original order; pad with
// first hit (0 if none).
// ---------------------------------------------------------------------------
__global__ __launch_bounds__(256) void ballq_kernel(const float* __restrict__ xyz,
                                                    const float* __restrict__ nxyz,
                                                    int* __restrict__ idx0,
                                                    int* __restrict__ idx1) {
  const int wid = threadIdx.x >> 6, lane = threadIdx.x & 63;
  const int bs = blockIdx.x * 4 + wid;
  const int b = bs >> 11;  // S = 2048
  const float* xb = xyz + (size_t)b * Nn * 3;
  const double cx = (double)nxyz[bs * 3 + 0];
  const double cy = (double)nxyz[bs * 3 + 1];
  const double cz = (double)nxyz[bs * 3 + 2];
  const double R0 = 0.4 * 0.4, R1 = 0.8 * 0.8;
  int cnt0 = 0, cnt1 = 0, first0 = 0, first1 = 0;
  const unsigned long long lmask = (1ull << lane) - 1ull;
  for (int base = 0; base < Nn; base += 64) {
    const int p = base + lane;
    double dx = __dsub_rn((double)xb[p * 3 + 0], cx);
    double dy = __dsub_rn((double)xb[p * 3 + 1], cy);
    double dz = __dsub_rn((double)xb[p * 3 + 2], cz);
    double d2 = __dadd_rn(__dadd_rn(__dmul_rn(dx, dx), __dmul_rn(dy, dy)), __dmul_rn(dz, dz));
    const bool in0 = d2 < R0, in1 = d2 < R1;
    unsigned long long m0 = __ballot(in0);
    unsigned long long m1 = __ballot(in1);
    if (cnt0 < 16 && m0) {
      if (cnt0 == 0) first0 = base + __builtin_ctzll(m0);
      int r = (int)__popcll(m0 & lmask);
      if (in0 && cnt0 + r < 16) idx0[bs * 16 + cnt0 + r] = p;
      cnt0 += (int)__popcll(m0);
    }
    if (cnt1 < 32 && m1) {
      if (cnt1 == 0) first1 = base + __builtin_ctzll(m1);
      int r = (int)__popcll(m1 & lmask);
      if (in1 && cnt1 + r < 32) idx1[bs * 32 + cnt1 + r] = p;
      cnt1 += (int)__popcll(m1);
    }
    if (cnt0 >= 16 && cnt1 >= 32) break;
  }
  const int f0 = cnt0 < 16 ? cnt0 : 16;
  for (int j = f0 + lane; j < 16; j += 64) idx0[bs * 16 + j] = first0;
  const int f1 = cnt1 < 32 ? cnt1 : 32;
  for (int j = f1 + lane; j < 32; j += 64) idx1[bs * 32 + j] = first1;
}

// ---------------------------------------------------------------------------
// Generic tall-skinny GEMM with fused input transforms and BN-stat partials.
// Tile: 64 rows x COUT cols, 256 threads, per-thread 4 rows x (COUT/16) cols.
// MODE 0: gather (rel-xyz ++ features) via ball-query idx          (K=67)
// MODE 1: x = relu(bn(prev_raw)) from 64-ch buffer (in-place safe) (K=64)
// MODE 2: x = concat(relu(bn(pool0)), relu(bn(pool1)))             (K=256)
// MODE 3: x = plain read (already-normalized h)                    (K=256)
// POOL  : write per-group (NS) max of raw output instead of full rows.
// Every block writes per-channel (sum, sumsq) partials to P[ch][block].
// ---------------------------------------------------------------------------
template <int COUT, int KTOT, int MODE, int NS, bool POOL, bool BIAS>
__global__ __launch_bounds__(256) void mlp_gemm(
    const float* __restrict__ xin, const float* __restrict__ xin2,
    const float* __restrict__ bnp, const float* __restrict__ bnp2,
    const float* __restrict__ w, const float* __restrict__ bias,
    const int* __restrict__ gidx, const float* __restrict__ xyz,
    const float* __restrict__ nxyz, const float* __restrict__ feats,
    float* __restrict__ out, float* __restrict__ P) {
  constexpr int KC = (KTOT <= 68) ? KTOT : 32;     // K chunk
  constexpr int NCH = (KTOT + KC - 1) / KC;
  constexpr int TC = COUT / 16;                    // cols per thread
  constexpr int XPAD = KC + 1;
  constexpr int XSZ = 64 * XPAD;
  constexpr int EPI = (POOL ? 48 : 32) * COUT;
  constexpr int SM = (XSZ + KC * COUT > EPI) ? (XSZ + KC * COUT) : EPI;
  __shared__ float smem[SM];
  float* xS = smem;
  float* wS = smem + XSZ;

  const int tid = threadIdx.x;
  const int cg = tid & 15, rg = tid >> 4;
  const int row0 = blockIdx.x * 64;
  float acc[4][TC];
#pragma unroll
  for (int i = 0; i < 4; ++i)
#pragma unroll
    for (int t = 0; t < TC; ++t) acc[i][t] = 0.f;

  for (int ch = 0; ch < NCH; ++ch) {
    const int k0 = ch * KC;
    if (ch) __syncthreads();
    // ---- stage x tile [64 rows][KC] (row-major, padded) ----
    for (int e = tid; e < 64 * KC; e += 256) {
      const int r = e / KC, kk = e - r * KC;
      const int kg = k0 + kk;
      const int rowg = row0 + r;
      float v;
      if constexpr (MODE == 0) {
        const int bs = rowg / NS;
        const int p = gidx[rowg];
        const int bb = bs >> 11;
        if (kg < 3)
          v = xyz[(bb * Nn + p) * 3 + kg] - nxyz[bs * 3 + kg];
        else
          v = feats[((bb * Nn + p) << 6) + (kg - 3)];
      } else if constexpr (MODE == 1) {
        v = fmaxf((xin[(size_t)rowg * 64 + kg] - bnp[kg]) * bnp[64 + kg], 0.f);
      } else if constexpr (MODE == 2) {
        if (kg < 128)
          v = fmaxf((xin[(size_t)rowg * 128 + kg] - bnp[kg]) * bnp[128 + kg], 0.f);
        else {
          const int k2 = kg - 128;
          v = fmaxf((xin2[(size_t)rowg * 128 + k2] - bnp2[k2]) * bnp2[128 + k2], 0.f);
        }
      } else {
        v = xin[(size_t)rowg * 256 + kg];
      }
      xS[r * XPAD + kk] = v;
    }
    // ---- stage w chunk [KC][COUT] ----
    for (int e = tid; e < KC * COUT; e += 256) {
      const int kk = e / COUT, c = e - kk * COUT;
      wS[kk * COUT + c] = w[(size_t)(k0 + kk) * COUT + c];
    }
    __syncthreads();
    // ---- FMA loop ----
    for (int kk = 0; kk < KC; ++kk) {
      float xr[4];
#pragma unroll
      for (int i = 0; i < 4; ++i) xr[i] = xS[(rg * 4 + i) * XPAD + kk];
#pragma unroll
      for (int t = 0; t < TC; t += 4) {
        const float4 wv = *(const float4*)&wS[kk * COUT + cg * TC + t];
#pragma unroll
        for (int i = 0; i < 4; ++i) {
          acc[i][t + 0] = fmaf(xr[i], wv.x, acc[i][t + 0]);
          acc[i][t + 1] = fmaf(xr[i], wv.y, acc[i][t + 1]);
          acc[i][t + 2] = fmaf(xr[i], wv.z, acc[i][t + 2]);
          acc[i][t + 3] = fmaf(xr[i], wv.w, acc[i][t + 3]);
        }
      }
    }
  }
  __syncthreads();  // smem reuse below
  if constexpr (BIAS) {
#pragma unroll
    for (int t = 0; t < TC; ++t) {
      const float bv = bias[cg * TC + t];
#pragma unroll
      for (int i = 0; i < 4; ++i) acc[i][t] += bv;
    }
  }
  // ---- per-block BN partials (+ group max for POOL) ----
  float* ssum = smem;
  float* ssq = smem + 16 * COUT;
  float* pbuf = smem + 32 * COUT;
  const int colb = cg * TC;
#pragma unroll
  for (int t = 0; t < TC; ++t) {
    float s = 0.f, q = 0.f, m = -3.4e38f;
#pragma unroll
    for (int i = 0; i < 4; ++i) {
      const float v = acc[i][t];
      s += v;
      q = fmaf(v, v, q);
      m = fmaxf(m, v);
    }
    ssum[rg * COUT + colb + t] = s;
    ssq[rg * COUT + colb + t] = q;
    if constexpr (POOL) pbuf[rg * COUT + colb + t] = m;
  }
  __syncthreads();
  const int gX = gridDim.x;
  for (int c = tid; c < COUT; c += 256) {
    float s = 0.f, q = 0.f;
#pragma unroll
    for (int rr = 0; rr < 16; ++rr) {
      s += ssum[rr * COUT + c];
      q += ssq[rr * COUT + c];
    }
    P[(size_t)c * gX + blockIdx.x] = s;
    P[(size_t)(COUT + c) * gX + blockIdx.x] = q;
  }
  if constexpr (POOL) {
    constexpr int G = 64 / NS, RPG = NS / 4;
    for (int o = tid; o < G * COUT; o += 256) {
      const int g = o / COUT, c = o - g * COUT;
      float m = pbuf[(g * RPG) * COUT + c];
#pragma unroll
      for (int qq = 1; qq < RPG; ++qq) m = fmaxf(m, pbuf[(g * RPG + qq) * COUT + c]);
      out[(size_t)(blockIdx.x * G + g) * COUT + c] = m;
    }
  } else {
#pragma unroll
    for (int i = 0; i < 4; ++i) {
      float* op = out + (size_t)(row0 + rg * 4 + i) * COUT + colb;
#pragma unroll
      for (int t = 0; t < TC; t += 4) {
        *(float4*)(op + t) = make_float4(acc[i][t], acc[i][t + 1], acc[i][t + 2], acc[i][t + 3]);
      }
    }
  }
}

// ---------------------------------------------------------------------------
// BN finalize: one block per channel, coalesced partial reads, deterministic
// f64 LDS tree reduction -> mu, rstd. bnp layout: [mu(C), rstd(C)].
// ---------------------------------------------------------------------------
__global__ __launch_bounds__(256) void bn_finalize(const float* __restrict__ P, int gX,
                                                   int M, int C, float* __restrict__ bnp) {
  __shared__ double sh[512];
  const int c = blockIdx.x;
  const int tid = threadIdx.x;
  const float* psum = P + (size_t)c * gX;
  const float* psq = P + (size_t)(C + c) * gX;
  double s = 0, q = 0;
  for (int i = tid; i < gX; i += 256) {
    s += (double)psum[i];
    q += (double)psq[i];
  }
  sh[tid] = s;
  sh[256 + tid] = q;
  __syncthreads();
  for (int off = 128; off; off >>= 1) {
    if (tid < off) {
      sh[tid] += sh[tid + off];
      sh[256 + tid] += sh[256 + tid + off];
    }
    __syncthreads();
  }
  if (tid == 0) {
    const double invM = 1.0 / (double)M;
    const double mu = sh[0] * invM;
    const double var = sh[256] * invM - mu * mu;
    bnp[c] = (float)mu;
    bnp[C + c] = (float)(1.0 / sqrt(var + 1e-5));
  }
}

// h = relu(bn(agg_raw)) -> d_out (also consumed by conf layer)
__global__ __launch_bounds__(256) void h_store_kernel(const float* __restrict__ agg,
                                                      const float* __restrict__ bnp,
                                                      float* __restrict__ hout) {
  const int t = blockIdx.x * 256 + threadIdx.x;
  const int c = t & 255;
  const float v = (agg[t] - bnp[c]) * bnp[256 + c];
  hout[t] = fmaxf(v, 0.f);
}

// cls = relu(bn(conf_raw)) @ cls_w + cls_b   (one wave per row)
__global__ __launch_bounds__(256) void cls_kernel(const float* __restrict__ craw,
                                                  const float* __restrict__ bnp,
                                                  const float* __restrict__ clsw,
                                                  const float* __restrict__ clsb,
                                                  float* __restrict__ outc) {
  const int wid = threadIdx.x >> 6, lane = threadIdx.x & 63;
  const int row = blockIdx.x * 4 + wid;
  const float* cr = craw + (size_t)row * 256;
  float a0 = 0.f, a1 = 0.f, a2 = 0.f;
#pragma unroll 4
  for (int k = lane; k < 256; k += 64) {
    float x = fmaxf((cr[k] - bnp[k]) * bnp[256 + k], 0.f);
    a0 = fmaf(x, clsw[k * 3 + 0], a0);
    a1 = fmaf(x, clsw[k * 3 + 1], a1);
    a2 = fmaf(x, clsw[k * 3 + 2], a2);
  }
#pragma unroll
  for (int off = 32; off; off >>= 1) {
    a0 += __shfl_down(a0, off);
    a1 += __shfl_down(a1, off);
    a2 += __shfl_down(a2, off);
  }
  if (lane == 0) {
    outc[row * 3 + 0] = a0 + clsb[0];
    outc[row * 3 + 1] = a1 + clsb[1];
    outc[row * 3 + 2] = a2 + clsb[2];
  }
}

// ---------------------------------------------------------------------------
extern "C" void kernel_launch(void* const* d_in, const int* in_sizes, int n_in,
                              void* d_out, int out_size, void* d_ws, size_t ws_size,
                              hipStream_t stream) {
  (void)in_sizes; (void)n_in; (void)out_size; (void)ws_size;
  const float* xyz = (const float*)d_in[0];
  const float* feats = (const float*)d_in[1];
  const float* w00 = (const float*)d_in[2];
  const float* w01 = (const float*)d_in[3];
  const float* w02 = (const float*)d_in[4];
  const float* w10 = (const float*)d_in[5];
  const float* w11 = (const float*)d_in[6];
  const float* w12 = (const float*)d_in[7];
  const float* aggw = (const float*)d_in[8];
  const float* aggb = (const float*)d_in[9];
  const float* confw = (const float*)d_in[10];
  const float* clsw = (const float*)d_in[11];
  const float* clsb = (const float*)d_in[12];

  float* outp = (float*)d_out;
  float* nxyz = outp;                               // [BS,3]
  float* hout = outp + (size_t)BS * 3;              // [BS,256]
  float* clsout = hout + (size_t)BS * 256;          // [BS,3]

  char* ws = (char*)d_ws;
  const size_t MB = 1u << 20;
  int* idx0 = (int*)(ws + 0);                       // 1 MB
  int* idx1 = (int*)(ws + 1 * MB);                  // 2 MB
  float* bnb = (float*)(ws + 3 * MB);               // bn params (2048 floats)
  float* P = (float*)(ws + 4 * MB);                 // partials, up to 8 MB
  float* pool0 = (float*)(ws + 12 * MB);            // [BS,128]
  float* pool1 = (float*)(ws + 20 * MB);            // [BS,128]
  float* aggraw = (float*)(ws + 28 * MB);           // [BS,256]
  float* confraw = (float*)(ws + 44 * MB);          // [BS,256]
  float* hA = (float*)(ws + 60 * MB);               // [524288,64] (layers 1/2 in-place)

  fps_kernel<<<Bb, 512, 0, stream>>>(xyz, nxyz);
  ballq_kernel<<<BS / 4, 256, 0, stream>>>(xyz, nxyz, idx0, idx1);

  // ---- scale 0 (r=0.4, ns=16), M = 262144 ----
  mlp_gemm<64, 67, 0, 16, false, false><<<4096, 256, 0, stream>>>(
      nullptr, nullptr, nullptr, nullptr, w00, nullptr, idx0, xyz, nxyz, feats, hA, P);
  bn_finalize<<<64, 256, 0, stream>>>(P, 4096, 262144, 64, bnb + 0);
  mlp_gemm<64, 64, 1, 1, false, false><<<4096, 256, 0, stream>>>(
      hA, nullptr, bnb + 0, nullptr, w01, nullptr, nullptr, nullptr, nullptr, nullptr, hA, P);
  bn_finalize<<<64, 256, 0, stream>>>(P, 4096, 262144, 64, bnb + 128);
  mlp_gemm<128, 64, 1, 16, true, false><<<4096, 256, 0, stream>>>(
      hA, nullptr, bnb + 128, nullptr, w02, nullptr, nullptr, nullptr, nullptr, nullptr, pool0, P);
  bn_finalize<<<128, 256, 0, stream>>>(P, 4096, 262144, 128, bnb + 256);

  // ---- scale 1 (r=0.8, ns=32), M = 524288 ----
  mlp_gemm<64, 67, 0, 32, false, false><<<8192, 256, 0, stream>>>(
      nullptr, nullptr, nullptr, nullptr, w10, nullptr, idx1, xyz, nxyz, feats, hA, P);
  bn_finalize<<<64, 256, 0, stream>>>(P, 8192, 524288, 64, bnb + 512);
  mlp_gemm<64, 64, 1, 1, false, false><<<8192, 256, 0, stream>>>(
      hA, nullptr, bnb + 512, nullptr, w11, nullptr, nullptr, nullptr, nullptr, nullptr, hA, P);
  bn_finalize<<<64, 256, 0, stream>>>(P, 8192, 524288, 64, bnb + 640);
  mlp_gemm<128, 64, 1, 32, true, false><<<8192, 256, 0, stream>>>(
      hA, nullptr, bnb + 640, nullptr, w12, nullptr, nullptr, nullptr, nullptr, nullptr, pool1, P);
  bn_finalize<<<128, 256, 0, stream>>>(P, 8192, 524288, 128, bnb + 768);

  // ---- aggregation: concat(bn3_0(pool0), bn3_1(pool1)) @ agg_w + agg_b ----
  mlp_gemm<256, 256, 2, 1, false, true><<<256, 256, 0, stream>>>(
      pool0, pool1, bnb + 256, bnb + 768, aggw, aggb, nullptr, nullptr, nullptr, nullptr, aggraw, P);
  bn_finalize<<<256, 256, 0, stream>>>(P, 256, 16384, 256, bnb + 1024);
  h_store_kernel<<<BS, 256, 0, stream>>>(aggraw, bnb + 1024, hout);

  // ---- confidence hidden layer ----
  mlp_gemm<256, 256, 3, 1, false, false><<<256, 256, 0, stream>>>(
      hout, nullptr, nullptr, nullptr, confw, nullptr, nullptr, nullptr, nullptr, nullptr, confraw, P);
  bn_finalize<<<256, 256, 0, stream>>>(P, 256, 16384, 256, bnb + 1536);

  // ---- classifier ----
  cls_kernel<<<BS / 4, 256, 0, stream>>>(confraw, bnb + 1536, clsw, clsb, clsout);
}

// Round 9
// 3854.937 us; speedup vs baseline: 1.4835x; 1.1719x over previous
//
#include <hip/hip_runtime.h>
#include <cstdint>
#include <cstddef>

// Problem constants (fixed by reference setup_inputs)
constexpr int Bb = 8;
constexpr int Nn = 8192;
constexpr int Ss = 2048;
constexpr int BS = Bb * Ss;  // 16384

typedef float vfloat2 __attribute__((ext_vector_type(2)));

// ---------------------------------------------------------------------------
// FPS: one block per batch, 1024 threads, 8 points/thread (r5 shape — proven
// best: enough waves/SIMD to hide latency, no spills at ~75 live VGPRs).
// dist[] updates exact f64 (bit-matches np, verified r1-r8); certified f32
// screening (distf = (float)dist * 1.000002 upper bound) skips only provable
// non-updates.
// Round-9: block argmax via LDS 64-bit atomics — EXACT by construction:
//   - non-negative f64 bits are monotone as u64 -> atomicMax(slotV, bits)
//     by each wave's lane0 yields the exact global max (no f32 fallbacks);
//   - lanes with lv == W do atomicMin(slotI, li) -> smallest original index
//     among exact ties == np.argmax semantics.
// Wave stage is value-only f64 max (6 shuffles), run only when the wave's
// ballot reports a change; cached wave max otherwise. Two barriers/iter with
// parity slots; reset of the other parity folded into phase 2.
// ---------------------------------------------------------------------------
__global__ __launch_bounds__(1024) void fps_kernel(const float* __restrict__ xyz,
                                                   float* __restrict__ new_xyz) {
  __shared__ float lx[Nn * 3];             // 96 KB: batch point cloud
  __shared__ int sidx[Ss];                 // 8 KB: selected-index log
  __shared__ unsigned long long slotV[2];  // parity: f64-bit global max
  __shared__ int slotI[2];                 // parity: winner index (min over ties)
  const int b = blockIdx.x;
  const int tid = threadIdx.x;
  const float* xb = xyz + (size_t)b * Nn * 3;
  for (int e = tid; e < Nn * 3; e += 1024) lx[e] = xb[e];
  if (tid == 0) {
    slotV[0] = 0ull; slotV[1] = 0ull;
    slotI[0] = 0x7fffffff; slotI[1] = 0x7fffffff;
  }
  __syncthreads();

  vfloat2 px2[4], py2[4], pz2[4], df2[4];
  double dist[8];
#pragma unroll
  for (int jj = 0; jj < 4; ++jj) {
    const int p0 = tid + (2 * jj) * 1024, p1 = tid + (2 * jj + 1) * 1024;
    px2[jj] = (vfloat2){lx[p0 * 3 + 0], lx[p1 * 3 + 0]};
    py2[jj] = (vfloat2){lx[p0 * 3 + 1], lx[p1 * 3 + 1]};
    pz2[jj] = (vfloat2){lx[p0 * 3 + 2], lx[p1 * 3 + 2]};
    df2[jj] = (vfloat2){3.0e38f, 3.0e38f};   // force exact path on first touch
    dist[2 * jj] = 1e10;
    dist[2 * jj + 1] = 1e10;
  }
  const int lane = tid & 63;
  int cur = 0;
  double lv = 0.0;                         // per-lane cached local max (exact);
  int li = 0x7fffffff;                     // real after i=0 (all lanes change)
  double wv_c = 0.0;                       // cached wave value-max
  for (int i = 0; i < Ss; ++i) {
    if (tid == 0) sidx[i] = cur;           // LDS log (visible after barrier)
    const float cxf = lx[cur * 3 + 0], cyf = lx[cur * 3 + 1], czf = lx[cur * 3 + 2];
    const vfloat2 cx2 = {cxf, cxf}, cy2 = {cyf, cyf}, cz2 = {czf, czf};
    // ---- packed-f32 screening: which j might update? ----
    unsigned need = 0;
#pragma unroll
    for (int jj = 0; jj < 4; ++jj) {
      const vfloat2 dx = px2[jj] - cx2;
      const vfloat2 dy = py2[jj] - cy2;
      const vfloat2 dz = pz2[jj] - cz2;
      const vfloat2 d2 = dx * dx + dy * dy + dz * dz;
      need |= (d2.x <= df2[jj].x) ? (1u << (2 * jj)) : 0u;
      need |= (d2.y <= df2[jj].y) ? (1u << (2 * jj + 1)) : 0u;
    }
    bool changed = false;
    if (need) {                            // rare path: exact f64 updates
#pragma unroll
      for (int j = 0; j < 8; ++j) {
        if (need & (1u << j)) {
          const float pxs = px2[j >> 1][j & 1];
          const float pys = py2[j >> 1][j & 1];
          const float pzs = pz2[j >> 1][j & 1];
          double dx = __dsub_rn((double)pxs, (double)cxf);
          double dy = __dsub_rn((double)pys, (double)cyf);
          double dz = __dsub_rn((double)pzs, (double)czf);
          double d = __dadd_rn(__dadd_rn(__dmul_rn(dx, dx), __dmul_rn(dy, dy)),
                               __dmul_rn(dz, dz));
          if (d < dist[j]) {
            dist[j] = d;
            const float dfn = (float)d * 1.000002f;  // certified upper bound
            if (j & 1) df2[j >> 1].y = dfn; else df2[j >> 1].x = dfn;
            changed = true;
          }
        }
      }
    }
    const unsigned long long anyb = __ballot(changed);
    if (changed) {                         // rescan local max only when needed
      lv = -1.0;
      li = 0;
#pragma unroll
      for (int j = 0; j < 8; ++j) {
        if (dist[j] > lv) { lv = dist[j]; li = tid + j * 1024; }  // j asc => smallest idx on tie
      }
    }
    if (anyb) {                            // wave value-only f64 max (no index)
      double bv = lv;
#pragma unroll
      for (int off = 1; off < 64; off <<= 1) bv = fmax(bv, __shfl_xor(bv, off));
      wv_c = bv;
    }
    const int pb = i & 1;
    if (lane == 0) atomicMax(&slotV[pb], __double_as_longlong(wv_c));
    __syncthreads();
    // ---- winner identification: exact compare + min-index atomic ----
    const double W = __longlong_as_double((long long)slotV[pb]);
    if (lv == W) atomicMin(&slotI[pb], li);
    if (tid == 0) {                        // reset other parity for iter i+1
      slotV[pb ^ 1] = 0ull;
      slotI[pb ^ 1] = 0x7fffffff;
    }
    __syncthreads();
    cur = slotI[pb];
  }
  __syncthreads();
  // final gather: new_xyz[i][c] = lx[sidx[i]*3 + c]
  float* nxb = new_xyz + (size_t)b * Ss * 3;
  for (int e = tid; e < Ss * 3; e += 1024) {
    const int i = e / 3, c = e - i * 3;
    nxb[e] = lx[sidx[i] * 3 + c];
  }
}

// ---------------------------------------------------------------------------
// Ball query, both scales fused. One wave per center. f64 distance compare
// (bit-matches np). First nsample in-range points in original order; pad with
// first hit (0 if none).
// ---------------------------------------------------------------------------
__global__ __launch_bounds__(256) void ballq_kernel(const float* __restrict__ xyz,
                                                    const float* __restrict__ nxyz,
                                                    int* __restrict__ idx0,
                                                    int* __restrict__ idx1) {
  const int wid = threadIdx.x >> 6, lane = threadIdx.x & 63;
  const int bs = blockIdx.x * 4 + wid;
  const int b = bs >> 11;  // S = 2048
  const float* xb = xyz + (size_t)b * Nn * 3;
  const double cx = (double)nxyz[bs * 3 + 0];
  const double cy = (double)nxyz[bs * 3 + 1];
  const double cz = (double)nxyz[bs * 3 + 2];
  const double R0 = 0.4 * 0.4, R1 = 0.8 * 0.8;
  int cnt0 = 0, cnt1 = 0, first0 = 0, first1 = 0;
  const unsigned long long lmask = (1ull << lane) - 1ull;
  for (int base = 0; base < Nn; base += 64) {
    const int p = base + lane;
    double dx = __dsub_rn((double)xb[p * 3 + 0], cx);
    double dy = __dsub_rn((double)xb[p * 3 + 1], cy);
    double dz = __dsub_rn((double)xb[p * 3 + 2], cz);
    double d2 = __dadd_rn(__dadd_rn(__dmul_rn(dx, dx), __dmul_rn(dy, dy)), __dmul_rn(dz, dz));
    const bool in0 = d2 < R0, in1 = d2 < R1;
    unsigned long long m0 = __ballot(in0);
    unsigned long long m1 = __ballot(in1);
    if (cnt0 < 16 && m0) {
      if (cnt0 == 0) first0 = base + __builtin_ctzll(m0);
      int r = (int)__popcll(m0 & lmask);
      if (in0 && cnt0 + r < 16) idx0[bs * 16 + cnt0 + r] = p;
      cnt0 += (int)__popcll(m0);
    }
    if (cnt1 < 32 && m1) {
      if (cnt1 == 0) first1 = base + __builtin_ctzll(m1);
      int r = (int)__popcll(m1 & lmask);
      if (in1 && cnt1 + r < 32) idx1[bs * 32 + cnt1 + r] = p;
      cnt1 += (int)__popcll(m1);
    }
    if (cnt0 >= 16 && cnt1 >= 32) break;
  }
  const int f0 = cnt0 < 16 ? cnt0 : 16;
  for (int j = f0 + lane; j < 16; j += 64) idx0[bs * 16 + j] = first0;
  const int f1 = cnt1 < 32 ? cnt1 : 32;
  for (int j = f1 + lane; j < 32; j += 64) idx1[bs * 32 + j] = first1;
}

// ---------------------------------------------------------------------------
// Generic tall-skinny GEMM with fused input transforms and BN-stat partials.
// Tile: 64 rows x COUT cols, 256 threads, per-thread 4 rows x (COUT/16) cols.
// MODE 0: gather (rel-xyz ++ features) via ball-query idx          (K=67)
// MODE 1: x = relu(bn(prev_raw)) from 64-ch buffer (in-place safe) (K=64)
// MODE 2: x = concat(relu(bn(pool0)), relu(bn(pool1)))             (K=256)
// MODE 3: x = plain read (already-normalized h)                    (K=256)
// POOL  : write per-group (NS) max of raw output instead of full rows.
// Every block writes per-channel (sum, sumsq) partials to P[ch][block].
// ---------------------------------------------------------------------------
template <int COUT, int KTOT, int MODE, int NS, bool POOL, bool BIAS>
__global__ __launch_bounds__(256) void mlp_gemm(
    const float* __restrict__ xin, const float* __restrict__ xin2,
    const float* __restrict__ bnp, const float* __restrict__ bnp2,
    const float* __restrict__ w, const float* __restrict__ bias,
    const int* __restrict__ gidx, const float* __restrict__ xyz,
    const float* __restrict__ nxyz, const float* __restrict__ feats,
    float* __restrict__ out, float* __restrict__ P) {
  constexpr int KC = (KTOT <= 68) ? KTOT : 32;     // K chunk
  constexpr int NCH = (KTOT + KC - 1) / KC;
  constexpr int TC = COUT / 16;                    // cols per thread
  constexpr int XPAD = KC + 1;
  constexpr int XSZ = 64 * XPAD;
  constexpr int EPI = (POOL ? 48 : 32) * COUT;
  constexpr int SM = (XSZ + KC * COUT > EPI) ? (XSZ + KC * COUT) : EPI;
  __shared__ float smem[SM];
  float* xS = smem;
  float* wS = smem + XSZ;

  const int tid = threadIdx.x;
  const int cg = tid & 15, rg = tid >> 4;
  const int row0 = blockIdx.x * 64;
  float acc[4][TC];
#pragma unroll
  for (int i = 0; i < 4; ++i)
#pragma unroll
    for (int t = 0; t < TC; ++t) acc[i][t] = 0.f;

  for (int ch = 0; ch < NCH; ++ch) {
    const int k0 = ch * KC;
    if (ch) __syncthreads();
    // ---- stage x tile [64 rows][KC] (row-major, padded) ----
    for (int e = tid; e < 64 * KC; e += 256) {
      const int r = e / KC, kk = e - r * KC;
      const int kg = k0 + kk;
      const int rowg = row0 + r;
      float v;
      if constexpr (MODE == 0) {
        const int bs = rowg / NS;
        const int p = gidx[rowg];
        const int bb = bs >> 11;
        if (kg < 3)
          v = xyz[(bb * Nn + p) * 3 + kg] - nxyz[bs * 3 + kg];
        else
          v = feats[((bb * Nn + p) << 6) + (kg - 3)];
      } else if constexpr (MODE == 1) {
        v = fmaxf((xin[(size_t)rowg * 64 + kg] - bnp[kg]) * bnp[64 + kg], 0.f);
      } else if constexpr (MODE == 2) {
        if (kg < 128)
          v = fmaxf((xin[(size_t)rowg * 128 + kg] - bnp[kg]) * bnp[128 + kg], 0.f);
        else {
          const int k2 = kg - 128;
          v = fmaxf((xin2[(size_t)rowg * 128 + k2] - bnp2[k2]) * bnp2[128 + k2], 0.f);
        }
      } else {
        v = xin[(size_t)rowg * 256 + kg];
      }
      xS[r * XPAD + kk] = v;
    }
    // ---- stage w chunk [KC][COUT] ----
    for (int e = tid; e < KC * COUT; e += 256) {
      const int kk = e / COUT, c = e - kk * COUT;
      wS[kk * COUT + c] = w[(size_t)(k0 + kk) * COUT + c];
    }
    __syncthreads();
    // ---- FMA loop ----
    for (int kk = 0; kk < KC; ++kk) {
      float xr[4];
#pragma unroll
      for (int i = 0; i < 4; ++i) xr[i] = xS[(rg * 4 + i) * XPAD + kk];
#pragma unroll
      for (int t = 0; t < TC; t += 4) {
        const float4 wv = *(const float4*)&wS[kk * COUT + cg * TC + t];
#pragma unroll
        for (int i = 0; i < 4; ++i) {
          acc[i][t + 0] = fmaf(xr[i], wv.x, acc[i][t + 0]);
          acc[i][t + 1] = fmaf(xr[i], wv.y, acc[i][t + 1]);
          acc[i][t + 2] = fmaf(xr[i], wv.z, acc[i][t + 2]);
          acc[i][t + 3] = fmaf(xr[i], wv.w, acc[i][t + 3]);
        }
      }
    }
  }
  __syncthreads();  // smem reuse below
  if constexpr (BIAS) {
#pragma unroll
    for (int t = 0; t < TC; ++t) {
      const float bv = bias[cg * TC + t];
#pragma unroll
      for (int i = 0; i < 4; ++i) acc[i][t] += bv;
    }
  }
  // ---- per-block BN partials (+ group max for POOL) ----
  float* ssum = smem;
  float* ssq = smem + 16 * COUT;
  float* pbuf = smem + 32 * COUT;
  const int colb = cg * TC;
#pragma unroll
  for (int t = 0; t < TC; ++t) {
    float s = 0.f, q = 0.f, m = -3.4e38f;
#pragma unroll
    for (int i = 0; i < 4; ++i) {
      const float v = acc[i][t];
      s += v;
      q = fmaf(v, v, q);
      m = fmaxf(m, v);
    }
    ssum[rg * COUT + colb + t] = s;
    ssq[rg * COUT + colb + t] = q;
    if constexpr (POOL) pbuf[rg * COUT + colb + t] = m;
  }
  __syncthreads();
  const int gX = gridDim.x;
  for (int c = tid; c < COUT; c += 256) {
    float s = 0.f, q = 0.f;
#pragma unroll
    for (int rr = 0; rr < 16; ++rr) {
      s += ssum[rr * COUT + c];
      q += ssq[rr * COUT + c];
    }
    P[(size_t)c * gX + blockIdx.x] = s;
    P[(size_t)(COUT + c) * gX + blockIdx.x] = q;
  }
  if constexpr (POOL) {
    constexpr int G = 64 / NS, RPG = NS / 4;
    for (int o = tid; o < G * COUT; o += 256) {
      const int g = o / COUT, c = o - g * COUT;
      float m = pbuf[(g * RPG) * COUT + c];
#pragma unroll
      for (int qq = 1; qq < RPG; ++qq) m = fmaxf(m, pbuf[(g * RPG + qq) * COUT + c]);
      out[(size_t)(blockIdx.x * G + g) * COUT + c] = m;
    }
  } else {
#pragma unroll
    for (int i = 0; i < 4; ++i) {
      float* op = out + (size_t)(row0 + rg * 4 + i) * COUT + colb;
#pragma unroll
      for (int t = 0; t < TC; t += 4) {
        *(float4*)(op + t) = make_float4(acc[i][t], acc[i][t + 1], acc[i][t + 2], acc[i][t + 3]);
      }
    }
  }
}

// ---------------------------------------------------------------------------
// BN finalize: one block per channel, coalesced partial reads, deterministic
// f64 LDS tree reduction -> mu, rstd. bnp layout: [mu(C), rstd(C)].
// ---------------------------------------------------------------------------
__global__ __launch_bounds__(256) void bn_finalize(const float* __restrict__ P, int gX,
                                                   int M, int C, float* __restrict__ bnp) {
  __shared__ double sh[512];
  const int c = blockIdx.x;
  const int tid = threadIdx.x;
  const float* psum = P + (size_t)c * gX;
  const float* psq = P + (size_t)(C + c) * gX;
  double s = 0, q = 0;
  for (int i = tid; i < gX; i += 256) {
    s += (double)psum[i];
    q += (double)psq[i];
  }
  sh[tid] = s;
  sh[256 + tid] = q;
  __syncthreads();
  for (int off = 128; off; off >>= 1) {
    if (tid < off) {
      sh[tid] += sh[tid + off];
      sh[256 + tid] += sh[256 + tid + off];
    }
    __syncthreads();
  }
  if (tid == 0) {
    const double invM = 1.0 / (double)M;
    const double mu = sh[0] * invM;
    const double var = sh[256] * invM - mu * mu;
    bnp[c] = (float)mu;
    bnp[C + c] = (float)(1.0 / sqrt(var + 1e-5));
  }
}

// h = relu(bn(agg_raw)) -> d_out (also consumed by conf layer)
__global__ __launch_bounds__(256) void h_store_kernel(const float* __restrict__ agg,
                                                      const float* __restrict__ bnp,
                                                      float* __restrict__ hout) {
  const int t = blockIdx.x * 256 + threadIdx.x;
  const int c = t & 255;
  const float v = (agg[t] - bnp[c]) * bnp[256 + c];
  hout[t] = fmaxf(v, 0.f);
}

// cls = relu(bn(conf_raw)) @ cls_w + cls_b   (one wave per row)
__global__ __launch_bounds__(256) void cls_kernel(const float* __restrict__ craw,
                                                  const float* __restrict__ bnp,
                                                  const float* __restrict__ clsw,
                                                  const float* __restrict__ clsb,
                                                  float* __restrict__ outc) {
  const int wid = threadIdx.x >> 6, lane = threadIdx.x & 63;
  const int row = blockIdx.x * 4 + wid;
  const float* cr = craw + (size_t)row * 256;
  float a0 = 0.f, a1 = 0.f, a2 = 0.f;
#pragma unroll 4
  for (int k = lane; k < 256; k += 64) {
    float x = fmaxf((cr[k] - bnp[k]) * bnp[256 + k], 0.f);
    a0 = fmaf(x, clsw[k * 3 + 0], a0);
    a1 = fmaf(x, clsw[k * 3 + 1], a1);
    a2 = fmaf(x, clsw[k * 3 + 2], a2);
  }
#pragma unroll
  for (int off = 32; off; off >>= 1) {
    a0 += __shfl_down(a0, off);
    a1 += __shfl_down(a1, off);
    a2 += __shfl_down(a2, off);
  }
  if (lane == 0) {
    outc[row * 3 + 0] = a0 + clsb[0];
    outc[row * 3 + 1] = a1 + clsb[1];
    outc[row * 3 + 2] = a2 + clsb[2];
  }
}

// ---------------------------------------------------------------------------
extern "C" void kernel_launch(void* const* d_in, const int* in_sizes, int n_in,
                              void* d_out, int out_size, void* d_ws, size_t ws_size,
                              hipStream_t stream) {
  (void)in_sizes; (void)n_in; (void)out_size; (void)ws_size;
  const float* xyz = (const float*)d_in[0];
  const float* feats = (const float*)d_in[1];
  const float* w00 = (const float*)d_in[2];
  const float* w01 = (const float*)d_in[3];
  const float* w02 = (const float*)d_in[4];
  const float* w10 = (const float*)d_in[5];
  const float* w11 = (const float*)d_in[6];
  const float* w12 = (const float*)d_in[7];
  const float* aggw = (const float*)d_in[8];
  const float* aggb = (const float*)d_in[9];
  const float* confw = (const float*)d_in[10];
  const float* clsw = (const float*)d_in[11];
  const float* clsb = (const float*)d_in[12];

  float* outp = (float*)d_out;
  float* nxyz = outp;                               // [BS,3]
  float* hout = outp + (size_t)BS * 3;              // [BS,256]
  float* clsout = hout + (size_t)BS * 256;          // [BS,3]

  char* ws = (char*)d_ws;
  const size_t MB = 1u << 20;
  int* idx0 = (int*)(ws + 0);                       // 1 MB
  int* idx1 = (int*)(ws + 1 * MB);                  // 2 MB
  float* bnb = (float*)(ws + 3 * MB);               // bn params (2048 floats)
  float* P = (float*)(ws + 4 * MB);                 // partials, up to 8 MB
  float* pool0 = (float*)(ws + 12 * MB);            // [BS,128]
  float* pool1 = (float*)(ws + 20 * MB);            // [BS,128]
  float* aggraw = (float*)(ws + 28 * MB);           // [BS,256]
  float* confraw = (float*)(ws + 44 * MB);          // [BS,256]
  float* hA = (float*)(ws + 60 * MB);               // [524288,64] (layers 1/2 in-place)

  fps_kernel<<<Bb, 1024, 0, stream>>>(xyz, nxyz);
  ballq_kernel<<<BS / 4, 256, 0, stream>>>(xyz, nxyz, idx0, idx1);

  // ---- scale 0 (r=0.4, ns=16), M = 262144 ----
  mlp_gemm<64, 67, 0, 16, false, false><<<4096, 256, 0, stream>>>(
      nullptr, nullptr, nullptr, nullptr, w00, nullptr, idx0, xyz, nxyz, feats, hA, P);
  bn_finalize<<<64, 256, 0, stream>>>(P, 4096, 262144, 64, bnb + 0);
  mlp_gemm<64, 64, 1, 1, false, false><<<4096, 256, 0, stream>>>(
      hA, nullptr, bnb + 0, nullptr, w01, nullptr, nullptr, nullptr, nullptr, nullptr, hA, P);
  bn_finalize<<<64, 256, 0, stream>>>(P, 4096, 262144, 64, bnb + 128);
  mlp_gemm<128, 64, 1, 16, true, false><<<4096, 256, 0, stream>>>(
      hA, nullptr, bnb + 128, nullptr, w02, nullptr, nullptr, nullptr, nullptr, nullptr, pool0, P);
  bn_finalize<<<128, 256, 0, stream>>>(P, 4096, 262144, 128, bnb + 256);

  // ---- scale 1 (r=0.8, ns=32), M = 524288 ----
  mlp_gemm<64, 67, 0, 32, false, false><<<8192, 256, 0, stream>>>(
      nullptr, nullptr, nullptr, nullptr, w10, nullptr, idx1, xyz, nxyz, feats, hA, P);
  bn_finalize<<<64, 256, 0, stream>>>(P, 8192, 524288, 64, bnb + 512);
  mlp_gemm<64, 64, 1, 1, false, false><<<8192, 256, 0, stream>>>(
      hA, nullptr, bnb + 512, nullptr, w11, nullptr, nullptr, nullptr, nullptr, nullptr, hA, P);
  bn_finalize<<<64, 256, 0, stream>>>(P, 8192, 524288, 64, bnb + 640);
  mlp_gemm<128, 64, 1, 32, true, false><<<8192, 256, 0, stream>>>(
      hA, nullptr, bnb + 640, nullptr, w12, nullptr, nullptr, nullptr, nullptr, nullptr, pool1, P);
  bn_finalize<<<128, 256, 0, stream>>>(P, 8192, 524288, 128, bnb + 768);

  // ---- aggregation: concat(bn3_0(pool0), bn3_1(pool1)) @ agg_w + agg_b ----
  mlp_gemm<256, 256, 2, 1, false, true><<<256, 256, 0, stream>>>(
      pool0, pool1, bnb + 256, bnb + 768, aggw, aggb, nullptr, nullptr, nullptr, nullptr, aggraw, P);
  bn_finalize<<<256, 256, 0, stream>>>(P, 256, 16384, 256, bnb + 1024);
  h_store_kernel<<<BS, 256, 0, stream>>>(aggraw, bnb + 1024, hout);

  // ---- confidence hidden layer ----
  mlp_gemm<256, 256, 3, 1, false, false><<<256, 256, 0, stream>>>(
      hout, nullptr, nullptr, nullptr, confw, nullptr, nullptr, nullptr, nullptr, nullptr, confraw, P);
  bn_finalize<<<256, 256, 0, stream>>>(P, 256, 16384, 256, bnb + 1536);

  // ---- classifier ----
  cls_kernel<<<BS / 4, 256, 0, stream>>>(confraw, bnb + 1536, clsw, clsb, clsout);
}

// Round 10
// 3761.678 us; speedup vs baseline: 1.5202x; 1.0248x over previous
//
#include <hip/hip_runtime.h>
#include <cstdint>
#include <cstddef>

// Problem constants (fixed by reference setup_inputs)
constexpr int Bb = 8;
constexpr int Nn = 8192;
constexpr int Ss = 2048;
constexpr int BS = Bb * Ss;  // 16384

typedef float vfloat2 __attribute__((ext_vector_type(2)));

// ---------------------------------------------------------------------------
// FPS: one block per batch, 1024 threads, 8 points/thread (proven shape).
// dist[] updates exact f64 (bit-matches np, verified r1-r9); certified f32
// screening skips only provable non-updates. Round-10 reduce (exact):
//  - lv32=(float)lv per lane; wave caches wv32_c (f32 6-step chain, only on
//    changed waves). Lanes with lv32==wv32_c post atomicMax(slotV, bits(lv)).
//    f64->f32 cast is monotone, so the true f64-max lane always posts ->
//    slotV == exact global max W. No collision fallbacks needed.
//  - lanes with lv == W atomicMin(slotI, li) -> np.argmax first-occurrence.
//  - dmin pre-screen: min over 8 packed d2 vs cached lmax (= max certified
//    upper bound). dmin>lmax proves no per-j screen can pass -> skip; the
//    per-j decision flow is bit-identical when entered.
// ---------------------------------------------------------------------------
__global__ __launch_bounds__(1024) void fps_kernel(const float* __restrict__ xyz,
                                                   float* __restrict__ new_xyz) {
  __shared__ float lx[Nn * 3];             // 96 KB: batch point cloud
  __shared__ int sidx[Ss];                 // 8 KB: selected-index log
  __shared__ unsigned long long slotV[2];  // parity: f64-bit global max
  __shared__ int slotI[2];                 // parity: winner index (min over ties)
  const int b = blockIdx.x;
  const int tid = threadIdx.x;
  const float* xb = xyz + (size_t)b * Nn * 3;
  for (int e = tid; e < Nn * 3; e += 1024) lx[e] = xb[e];
  if (tid == 0) {
    slotV[0] = 0ull; slotV[1] = 0ull;
    slotI[0] = 0x7fffffff; slotI[1] = 0x7fffffff;
  }
  __syncthreads();

  vfloat2 px2[4], py2[4], pz2[4], df2[4];
  double dist[8];
#pragma unroll
  for (int jj = 0; jj < 4; ++jj) {
    const int p0 = tid + (2 * jj) * 1024, p1 = tid + (2 * jj + 1) * 1024;
    px2[jj] = (vfloat2){lx[p0 * 3 + 0], lx[p1 * 3 + 0]};
    py2[jj] = (vfloat2){lx[p0 * 3 + 1], lx[p1 * 3 + 1]};
    pz2[jj] = (vfloat2){lx[p0 * 3 + 2], lx[p1 * 3 + 2]};
    df2[jj] = (vfloat2){3.0e38f, 3.0e38f};   // force exact path on first touch
    dist[2 * jj] = 1e10;
    dist[2 * jj + 1] = 1e10;
  }
  float lmax = 3.0e38f;                    // cached max of certified bounds
  int cur = 0;
  double lv = -1.0;                        // per-lane cached local max (exact)
  int li = 0x7fffffff;
  float lv32 = -1.0f;                      // cached (float)lv
  float wv32_c = -1.0f;                    // cached wave f32 max
  for (int i = 0; i < Ss; ++i) {
    if (tid == 0) sidx[i] = cur;           // LDS log (visible after barrier)
    const float cxf = lx[cur * 3 + 0], cyf = lx[cur * 3 + 1], czf = lx[cur * 3 + 2];
    const vfloat2 cx2 = {cxf, cxf}, cy2 = {cyf, cyf}, cz2 = {czf, czf};
    // ---- packed-f32 distances ----
    vfloat2 d2v[4];
#pragma unroll
    for (int jj = 0; jj < 4; ++jj) {
      const vfloat2 dx = px2[jj] - cx2;
      const vfloat2 dy = py2[jj] - cy2;
      const vfloat2 dz = pz2[jj] - cz2;
      d2v[jj] = dx * dx + dy * dy + dz * dz;
    }
    const float dmin = fminf(fminf(fminf(d2v[0].x, d2v[0].y), fminf(d2v[1].x, d2v[1].y)),
                             fminf(fminf(d2v[2].x, d2v[2].y), fminf(d2v[3].x, d2v[3].y)));
    bool changed = false;
    if (dmin <= lmax) {                    // necessary condition for any update
#pragma unroll
      for (int j = 0; j < 8; ++j) {
        const float d2s = d2v[j >> 1][j & 1];
        const float dfs = (j & 1) ? df2[j >> 1].y : df2[j >> 1].x;
        if (d2s <= dfs) {                  // certified screen -> exact f64
          const float pxs = px2[j >> 1][j & 1];
          const float pys = py2[j >> 1][j & 1];
          const float pzs = pz2[j >> 1][j & 1];
          double dx = __dsub_rn((double)pxs, (double)cxf);
          double dy = __dsub_rn((double)pys, (double)cyf);
          double dz = __dsub_rn((double)pzs, (double)czf);
          double d = __dadd_rn(__dadd_rn(__dmul_rn(dx, dx), __dmul_rn(dy, dy)),
                               __dmul_rn(dz, dz));
          if (d < dist[j]) {
            dist[j] = d;
            const float dfn = (float)d * 1.000002f;  // certified upper bound
            if (j & 1) df2[j >> 1].y = dfn; else df2[j >> 1].x = dfn;
            changed = true;
          }
        }
      }
      if (changed) {                       // rescan local max + refresh lmax
        lv = -1.0;
        li = 0;
#pragma unroll
        for (int j = 0; j < 8; ++j) {
          if (dist[j] > lv) { lv = dist[j]; li = tid + j * 1024; }  // j asc => min idx on tie
        }
        lv32 = (float)lv;
        lmax = fmaxf(fmaxf(fmaxf(df2[0].x, df2[0].y), fmaxf(df2[1].x, df2[1].y)),
                     fmaxf(fmaxf(df2[2].x, df2[2].y), fmaxf(df2[3].x, df2[3].y)));
      }
    }
    const unsigned long long anyb = __ballot(changed);
    if (anyb) {                            // refresh wave f32 max (value-only)
      float m32 = lv32;
#pragma unroll
      for (int off = 1; off < 64; off <<= 1) m32 = fmaxf(m32, __shfl_xor(m32, off));
      wv32_c = m32;
    }
    const int pb = i & 1;
    // candidate lanes (contain the exact f64 wave max by monotonicity)
    if (lv32 == wv32_c) atomicMax(&slotV[pb], (unsigned long long)__double_as_longlong(lv));
    __syncthreads();
    const double W = __longlong_as_double((long long)slotV[pb]);
    if (lv == W) atomicMin(&slotI[pb], li);
    if (tid == 0) {                        // reset other parity for iter i+1
      slotV[pb ^ 1] = 0ull;
      slotI[pb ^ 1] = 0x7fffffff;
    }
    __syncthreads();
    cur = slotI[pb];
  }
  __syncthreads();
  // final gather: new_xyz[i][c] = lx[sidx[i]*3 + c]
  float* nxb = new_xyz + (size_t)b * Ss * 3;
  for (int e = tid; e < Ss * 3; e += 1024) {
    const int i = e / 3, c = e - i * 3;
    nxb[e] = lx[sidx[i] * 3 + c];
  }
}

// ---------------------------------------------------------------------------
// Ball query, both scales fused. One wave per center. f64 distance compare
// (bit-matches np). First nsample in-range points in original order; pad with
// first hit (0 if none).
// ---------------------------------------------------------------------------
__global__ __launch_bounds__(256) void ballq_kernel(const float* __restrict__ xyz,
                                                    const float* __restrict__ nxyz,
                                                    int* __restrict__ idx0,
                                                    int* __restrict__ idx1) {
  const int wid = threadIdx.x >> 6, lane = threadIdx.x & 63;
  const int bs = blockIdx.x * 4 + wid;
  const int b = bs >> 11;  // S = 2048
  const float* xb = xyz + (size_t)b * Nn * 3;
  const double cx = (double)nxyz[bs * 3 + 0];
  const double cy = (double)nxyz[bs * 3 + 1];
  const double cz = (double)nxyz[bs * 3 + 2];
  const double R0 = 0.4 * 0.4, R1 = 0.8 * 0.8;
  int cnt0 = 0, cnt1 = 0, first0 = 0, first1 = 0;
  const unsigned long long lmask = (1ull << lane) - 1ull;
  for (int base = 0; base < Nn; base += 64) {
    const int p = base + lane;
    double dx = __dsub_rn((double)xb[p * 3 + 0], cx);
    double dy = __dsub_rn((double)xb[p * 3 + 1], cy);
    double dz = __dsub_rn((double)xb[p * 3 + 2], cz);
    double d2 = __dadd_rn(__dadd_rn(__dmul_rn(dx, dx), __dmul_rn(dy, dy)), __dmul_rn(dz, dz));
    const bool in0 = d2 < R0, in1 = d2 < R1;
    unsigned long long m0 = __ballot(in0);
    unsigned long long m1 = __ballot(in1);
    if (cnt0 < 16 && m0) {
      if (cnt0 == 0) first0 = base + __builtin_ctzll(m0);
      int r = (int)__popcll(m0 & lmask);
      if (in0 && cnt0 + r < 16) idx0[bs * 16 + cnt0 + r] = p;
      cnt0 += (int)__popcll(m0);
    }
    if (cnt1 < 32 && m1) {
      if (cnt1 == 0) first1 = base + __builtin_ctzll(m1);
      int r = (int)__popcll(m1 & lmask);
      if (in1 && cnt1 + r < 32) idx1[bs * 32 + cnt1 + r] = p;
      cnt1 += (int)__popcll(m1);
    }
    if (cnt0 >= 16 && cnt1 >= 32) break;
  }
  const int f0 = cnt0 < 16 ? cnt0 : 16;
  for (int j = f0 + lane; j < 16; j += 64) idx0[bs * 16 + j] = first0;
  const int f1 = cnt1 < 32 ? cnt1 : 32;
  for (int j = f1 + lane; j < 32; j += 64) idx1[bs * 32 + j] = first1;
}

// ---------------------------------------------------------------------------
// Generic tall-skinny GEMM with fused input transforms and BN-stat partials.
// Tile: 64 rows x COUT cols, 256 threads, per-thread 4 rows x (COUT/16) cols.
// MODE 0: gather (rel-xyz ++ features) via ball-query idx          (K=67)
// MODE 1: x = relu(bn(prev_raw)) from 64-ch buffer (in-place safe) (K=64)
// MODE 2: x = concat(relu(bn(pool0)), relu(bn(pool1)))             (K=256)
// MODE 4: x = relu(bn(xin)) from 256-ch buffer; also writes x to hw (K=256)
// POOL  : write per-group (NS) max of raw output instead of full rows.
// Every block writes per-channel (sum, sumsq) partials to P[ch][block].
// ---------------------------------------------------------------------------
template <int COUT, int KTOT, int MODE, int NS, bool POOL, bool BIAS>
__global__ __launch_bounds__(256) void mlp_gemm(
    const float* __restrict__ xin, const float* __restrict__ xin2,
    const float* __restrict__ bnp, const float* __restrict__ bnp2,
    const float* __restrict__ w, const float* __restrict__ bias,
    const int* __restrict__ gidx, const float* __restrict__ xyz,
    const float* __restrict__ nxyz, const float* __restrict__ feats,
    float* __restrict__ hw, float* __restrict__ out, float* __restrict__ P) {
  constexpr int KC = (KTOT <= 68) ? KTOT : 32;     // K chunk
  constexpr int NCH = (KTOT + KC - 1) / KC;
  constexpr int TC = COUT / 16;                    // cols per thread
  constexpr int XPAD = KC + 1;
  constexpr int XSZ = 64 * XPAD;
  constexpr int EPI = (POOL ? 48 : 32) * COUT;
  constexpr int SM = (XSZ + KC * COUT > EPI) ? (XSZ + KC * COUT) : EPI;
  __shared__ float smem[SM];
  float* xS = smem;
  float* wS = smem + XSZ;

  const int tid = threadIdx.x;
  const int cg = tid & 15, rg = tid >> 4;
  const int row0 = blockIdx.x * 64;
  float acc[4][TC];
#pragma unroll
  for (int i = 0; i < 4; ++i)
#pragma unroll
    for (int t = 0; t < TC; ++t) acc[i][t] = 0.f;

  for (int ch = 0; ch < NCH; ++ch) {
    const int k0 = ch * KC;
    if (ch) __syncthreads();
    // ---- stage x tile [64 rows][KC] (row-major, padded) ----
    for (int e = tid; e < 64 * KC; e += 256) {
      const int r = e / KC, kk = e - r * KC;
      const int kg = k0 + kk;
      const int rowg = row0 + r;
      float v;
      if constexpr (MODE == 0) {
        const int bs = rowg / NS;
        const int p = gidx[rowg];
        const int bb = bs >> 11;
        if (kg < 3)
          v = xyz[(bb * Nn + p) * 3 + kg] - nxyz[bs * 3 + kg];
        else
          v = feats[((bb * Nn + p) << 6) + (kg - 3)];
      } else if constexpr (MODE == 1) {
        v = fmaxf((xin[(size_t)rowg * 64 + kg] - bnp[kg]) * bnp[64 + kg], 0.f);
      } else if constexpr (MODE == 2) {
        if (kg < 128)
          v = fmaxf((xin[(size_t)rowg * 128 + kg] - bnp[kg]) * bnp[128 + kg], 0.f);
        else {
          const int k2 = kg - 128;
          v = fmaxf((xin2[(size_t)rowg * 128 + k2] - bnp2[k2]) * bnp2[128 + k2], 0.f);
        }
      } else {  // MODE 4
        v = fmaxf((xin[(size_t)rowg * 256 + kg] - bnp[kg]) * bnp[256 + kg], 0.f);
        hw[(size_t)rowg * 256 + kg] = v;
      }
      xS[r * XPAD + kk] = v;
    }
    // ---- stage w chunk [KC][COUT] ----
    for (int e = tid; e < KC * COUT; e += 256) {
      const int kk = e / COUT, c = e - kk * COUT;
      wS[kk * COUT + c] = w[(size_t)(k0 + kk) * COUT + c];
    }
    __syncthreads();
    // ---- FMA loop ----
    for (int kk = 0; kk < KC; ++kk) {
      float xr[4];
#pragma unroll
      for (int i = 0; i < 4; ++i) xr[i] = xS[(rg * 4 + i) * XPAD + kk];
#pragma unroll
      for (int t = 0; t < TC; t += 4) {
        const float4 wv = *(const float4*)&wS[kk * COUT + cg * TC + t];
#pragma unroll
        for (int i = 0; i < 4; ++i) {
          acc[i][t + 0] = fmaf(xr[i], wv.x, acc[i][t + 0]);
          acc[i][t + 1] = fmaf(xr[i], wv.y, acc[i][t + 1]);
          acc[i][t + 2] = fmaf(xr[i], wv.z, acc[i][t + 2]);
          acc[i][t + 3] = fmaf(xr[i], wv.w, acc[i][t + 3]);
        }
      }
    }
  }
  __syncthreads();  // smem reuse below
  if constexpr (BIAS) {
#pragma unroll
    for (int t = 0; t < TC; ++t) {
      const float bv = bias[cg * TC + t];
#pragma unroll
      for (int i = 0; i < 4; ++i) acc[i][t] += bv;
    }
  }
  // ---- per-block BN partials (+ group max for POOL) ----
  float* ssum = smem;
  float* ssq = smem + 16 * COUT;
  float* pbuf = smem + 32 * COUT;
  const int colb = cg * TC;
#pragma unroll
  for (int t = 0; t < TC; ++t) {
    float s = 0.f, q = 0.f, m = -3.4e38f;
#pragma unroll
    for (int i = 0; i < 4; ++i) {
      const float v = acc[i][t];
      s += v;
      q = fmaf(v, v, q);
      m = fmaxf(m, v);
    }
    ssum[rg * COUT + colb + t] = s;
    ssq[rg * COUT + colb + t] = q;
    if constexpr (POOL) pbuf[rg * COUT + colb + t] = m;
  }
  __syncthreads();
  const int gX = gridDim.x;
  for (int c = tid; c < COUT; c += 256) {
    float s = 0.f, q = 0.f;
#pragma unroll
    for (int rr = 0; rr < 16; ++rr) {
      s += ssum[rr * COUT + c];
      q += ssq[rr * COUT + c];
    }
    P[(size_t)c * gX + blockIdx.x] = s;
    P[(size_t)(COUT + c) * gX + blockIdx.x] = q;
  }
  if constexpr (POOL) {
    constexpr int G = 64 / NS, RPG = NS / 4;
    for (int o = tid; o < G * COUT; o += 256) {
      const int g = o / COUT, c = o - g * COUT;
      float m = pbuf[(g * RPG) * COUT + c];
#pragma unroll
      for (int qq = 1; qq < RPG; ++qq) m = fmaxf(m, pbuf[(g * RPG + qq) * COUT + c]);
      out[(size_t)(blockIdx.x * G + g) * COUT + c] = m;
    }
  } else {
#pragma unroll
    for (int i = 0; i < 4; ++i) {
      float* op = out + (size_t)(row0 + rg * 4 + i) * COUT + colb;
#pragma unroll
      for (int t = 0; t < TC; t += 4) {
        *(float4*)(op + t) = make_float4(acc[i][t], acc[i][t + 1], acc[i][t + 2], acc[i][t + 3]);
      }
    }
  }
}

// ---------------------------------------------------------------------------
// BN finalize: one block per channel, coalesced partial reads, deterministic
// f64 LDS tree reduction -> mu, rstd. bnp layout: [mu(C), rstd(C)].
// ---------------------------------------------------------------------------
__global__ __launch_bounds__(256) void bn_finalize(const float* __restrict__ P, int gX,
                                                   int M, int C, float* __restrict__ bnp) {
  __shared__ double sh[512];
  const int c = blockIdx.x;
  const int tid = threadIdx.x;
  const float* psum = P + (size_t)c * gX;
  const float* psq = P + (size_t)(C + c) * gX;
  double s = 0, q = 0;
  for (int i = tid; i < gX; i += 256) {
    s += (double)psum[i];
    q += (double)psq[i];
  }
  sh[tid] = s;
  sh[256 + tid] = q;
  __syncthreads();
  for (int off = 128; off; off >>= 1) {
    if (tid < off) {
      sh[tid] += sh[tid + off];
      sh[256 + tid] += sh[256 + tid + off];
    }
    __syncthreads();
  }
  if (tid == 0) {
    const double invM = 1.0 / (double)M;
    const double mu = sh[0] * invM;
    const double var = sh[256] * invM - mu * mu;
    bnp[c] = (float)mu;
    bnp[C + c] = (float)(1.0 / sqrt(var + 1e-5));
  }
}

// cls = relu(bn(conf_raw)) @ cls_w + cls_b   (one wave per row)
__global__ __launch_bounds__(256) void cls_kernel(const float* __restrict__ craw,
                                                  const float* __restrict__ bnp,
                                                  const float* __restrict__ clsw,
                                                  const float* __restrict__ clsb,
                                                  float* __restrict__ outc) {
  const int wid = threadIdx.x >> 6, lane = threadIdx.x & 63;
  const int row = blockIdx.x * 4 + wid;
  const float* cr = craw + (size_t)row * 256;
  float a0 = 0.f, a1 = 0.f, a2 = 0.f;
#pragma unroll 4
  for (int k = lane; k < 256; k += 64) {
    float x = fmaxf((cr[k] - bnp[k]) * bnp[256 + k], 0.f);
    a0 = fmaf(x, clsw[k * 3 + 0], a0);
    a1 = fmaf(x, clsw[k * 3 + 1], a1);
    a2 = fmaf(x, clsw[k * 3 + 2], a2);
  }
#pragma unroll
  for (int off = 32; off; off >>= 1) {
    a0 += __shfl_down(a0, off);
    a1 += __shfl_down(a1, off);
    a2 += __shfl_down(a2, off);
  }
  if (lane == 0) {
    outc[row * 3 + 0] = a0 + clsb[0];
    outc[row * 3 + 1] = a1 + clsb[1];
    outc[row * 3 + 2] = a2 + clsb[2];
  }
}

// ---------------------------------------------------------------------------
extern "C" void kernel_launch(void* const* d_in, const int* in_sizes, int n_in,
                              void* d_out, int out_size, void* d_ws, size_t ws_size,
                              hipStream_t stream) {
  (void)in_sizes; (void)n_in; (void)out_size; (void)ws_size;
  const float* xyz = (const float*)d_in[0];
  const float* feats = (const float*)d_in[1];
  const float* w00 = (const float*)d_in[2];
  const float* w01 = (const float*)d_in[3];
  const float* w02 = (const float*)d_in[4];
  const float* w10 = (const float*)d_in[5];
  const float* w11 = (const float*)d_in[6];
  const float* w12 = (const float*)d_in[7];
  const float* aggw = (const float*)d_in[8];
  const float* aggb = (const float*)d_in[9];
  const float* confw = (const float*)d_in[10];
  const float* clsw = (const float*)d_in[11];
  const float* clsb = (const float*)d_in[12];

  float* outp = (float*)d_out;
  float* nxyz = outp;                               // [BS,3]
  float* hout = outp + (size_t)BS * 3;              // [BS,256]
  float* clsout = hout + (size_t)BS * 256;          // [BS,3]

  char* ws = (char*)d_ws;
  const size_t MB = 1u << 20;
  int* idx0 = (int*)(ws + 0);                       // 1 MB
  int* idx1 = (int*)(ws + 1 * MB);                  // 2 MB
  float* bnb = (float*)(ws + 3 * MB);               // bn params (2048 floats)
  float* P = (float*)(ws + 4 * MB);                 // partials, up to 8 MB
  float* pool0 = (float*)(ws + 12 * MB);            // [BS,128]
  float* pool1 = (float*)(ws + 20 * MB);            // [BS,128]
  float* aggraw = (float*)(ws + 28 * MB);           // [BS,256]
  float* confraw = (float*)(ws + 44 * MB);          // [BS,256]
  float* hA = (float*)(ws + 60 * MB);               // [524288,64] (layers 1/2 in-place)

  fps_kernel<<<Bb, 1024, 0, stream>>>(xyz, nxyz);
  ballq_kernel<<<BS / 4, 256, 0, stream>>>(xyz, nxyz, idx0, idx1);

  // ---- scale 0 (r=0.4, ns=16), M = 262144 ----
  mlp_gemm<64, 67, 0, 16, false, false><<<4096, 256, 0, stream>>>(
      nullptr, nullptr, nullptr, nullptr, w00, nullptr, idx0, xyz, nxyz, feats, nullptr, hA, P);
  bn_finalize<<<64, 256, 0, stream>>>(P, 4096, 262144, 64, bnb + 0);
  mlp_gemm<64, 64, 1, 1, false, false><<<4096, 256, 0, stream>>>(
      hA, nullptr, bnb + 0, nullptr, w01, nullptr, nullptr, nullptr, nullptr, nullptr, nullptr, hA, P);
  bn_finalize<<<64, 256, 0, stream>>>(P, 4096, 262144, 64, bnb + 128);
  mlp_gemm<128, 64, 1, 16, true, false><<<4096, 256, 0, stream>>>(
      hA, nullptr, bnb + 128, nullptr, w02, nullptr, nullptr, nullptr, nullptr, nullptr, nullptr, pool0, P);
  bn_finalize<<<128, 256, 0, stream>>>(P, 4096, 262144, 128, bnb + 256);

  // ---- scale 1 (r=0.8, ns=32), M = 524288 ----
  mlp_gemm<64, 67, 0, 32, false, false><<<8192, 256, 0, stream>>>(
      nullptr, nullptr, nullptr, nullptr, w10, nullptr, idx1, xyz, nxyz, feats, nullptr, hA, P);
  bn_finalize<<<64, 256, 0, stream>>>(P, 8192, 524288, 64, bnb + 512);
  mlp_gemm<64, 64, 1, 1, false, false><<<8192, 256, 0, stream>>>(
      hA, nullptr, bnb + 512, nullptr, w11, nullptr, nullptr, nullptr, nullptr, nullptr, nullptr, hA, P);
  bn_finalize<<<64, 256, 0, stream>>>(P, 8192, 524288, 64, bnb + 640);
  mlp_gemm<128, 64, 1, 32, true, false><<<8192, 256, 0, stream>>>(
      hA, nullptr, bnb + 640, nullptr, w12, nullptr, nullptr, nullptr, nullptr, nullptr, nullptr, pool1, P);
  bn_finalize<<<128, 256, 0, stream>>>(P, 8192, 524288, 128, bnb + 768);

  // ---- aggregation: concat(bn3_0(pool0), bn3_1(pool1)) @ agg_w + agg_b ----
  mlp_gemm<256, 256, 2, 1, false, true><<<256, 256, 0, stream>>>(
      pool0, pool1, bnb + 256, bnb + 768, aggw, aggb, nullptr, nullptr, nullptr, nullptr, nullptr, aggraw, P);
  bn_finalize<<<256, 256, 0, stream>>>(P, 256, 16384, 256, bnb + 1024);

  // ---- confidence hidden layer (MODE 4: applies bn+relu to aggraw, writes h
  //      to d_out during staging, then GEMMs against conf_w) ----
  mlp_gemm<256, 256, 4, 1, false, false><<<256, 256, 0, stream>>>(
      aggraw, nullptr, bnb + 1024, nullptr, confw, nullptr, nullptr, nullptr, nullptr, nullptr, hout, confraw, P);
  bn_finalize<<<256, 256, 0, stream>>>(P, 256, 16384, 256, bnb + 1536);

  // ---- classifier ----
  cls_kernel<<<BS / 4, 256, 0, stream>>>(confraw, bnb + 1536, clsw, clsb, clsout);
}